// Round 1
// baseline (2052.998 us; speedup 1.0000x reference)
//
#include <hip/hip_runtime.h>
#include <math.h>

#define TGT 32400
#define KLEN 16896
#define EMBED 256
#define HEADS 8
#define HDIM 32
#define LN_EPS 1e-5f

// ---------------- wave helpers (wave64) ----------------
__device__ inline float wave_sum(float v) {
#pragma unroll
    for (int o = 32; o; o >>= 1) v += __shfl_xor(v, o);
    return v;
}
__device__ inline float wave_max(float v) {
#pragma unroll
    for (int o = 32; o; o >>= 1) v = fmaxf(v, __shfl_xor(v, o));
    return v;
}

// ---------------- fused 2-layer MLP ----------------
// Y[r][c] = (relu(X[r]@W1 + b1) @ W2 + b2) * scale
// X: (R,256), W1: (256,512), W2: (512,256). 16 rows per block, 256 threads.
#define MROWS 16
__global__ __launch_bounds__(256) void mlp_kernel(
    const float* __restrict__ X,
    const float* __restrict__ W1, const float* __restrict__ b1,
    const float* __restrict__ W2, const float* __restrict__ b2,
    float scale, float* __restrict__ Y)
{
    __shared__ float Xs[MROWS][EMBED];     // 16 KiB
    __shared__ float Hs[MROWS][2 * EMBED]; // 32 KiB
    const int t = threadIdx.x;
    const int row0 = blockIdx.x * MROWS;

    // load X tile (coalesced float4)
    {
        const float4* src = (const float4*)(X + (size_t)row0 * EMBED);
        float4* dst = (float4*)(&Xs[0][0]);
#pragma unroll
        for (int i = 0; i < 4; ++i) dst[t + 256 * i] = src[t + 256 * i];
    }
    __syncthreads();

    // phase 1: hidden = relu(X@W1 + b1). Each thread: cols {t, t+256}, all 16 rows.
    {
        float acc0[MROWS], acc1[MROWS];
#pragma unroll
        for (int r = 0; r < MROWS; ++r) { acc0[r] = 0.f; acc1[r] = 0.f; }
        for (int k4 = 0; k4 < EMBED / 4; ++k4) {
            float4 xv[MROWS];
#pragma unroll
            for (int r = 0; r < MROWS; ++r) xv[r] = *(const float4*)(&Xs[r][k4 * 4]);
            float w0[4], w1[4];
#pragma unroll
            for (int kk = 0; kk < 4; ++kk) {
                w0[kk] = W1[(size_t)(k4 * 4 + kk) * 512 + t];
                w1[kk] = W1[(size_t)(k4 * 4 + kk) * 512 + t + 256];
            }
#pragma unroll
            for (int r = 0; r < MROWS; ++r) {
                acc0[r] += xv[r].x * w0[0] + xv[r].y * w0[1] + xv[r].z * w0[2] + xv[r].w * w0[3];
                acc1[r] += xv[r].x * w1[0] + xv[r].y * w1[1] + xv[r].z * w1[2] + xv[r].w * w1[3];
            }
        }
        float bb0 = b1[t], bb1 = b1[t + 256];
#pragma unroll
        for (int r = 0; r < MROWS; ++r) {
            Hs[r][t]       = fmaxf(acc0[r] + bb0, 0.f);
            Hs[r][t + 256] = fmaxf(acc1[r] + bb1, 0.f);
        }
    }
    __syncthreads();

    // phase 2: out = hidden @ W2 + b2. Each thread: col t, all 16 rows.
    {
        float acc[MROWS];
#pragma unroll
        for (int r = 0; r < MROWS; ++r) acc[r] = 0.f;
        for (int k4 = 0; k4 < 512 / 4; ++k4) {
            float4 hv[MROWS];
#pragma unroll
            for (int r = 0; r < MROWS; ++r) hv[r] = *(const float4*)(&Hs[r][k4 * 4]);
            float w[4];
#pragma unroll
            for (int kk = 0; kk < 4; ++kk) w[kk] = W2[(size_t)(k4 * 4 + kk) * EMBED + t];
#pragma unroll
            for (int r = 0; r < MROWS; ++r) {
                acc[r] += hv[r].x * w[0] + hv[r].y * w[1] + hv[r].z * w[2] + hv[r].w * w[3];
            }
        }
        float bb = b2[t];
#pragma unroll
        for (int r = 0; r < MROWS; ++r) {
            Y[(size_t)(row0 + r) * EMBED + t] = (acc[r] + bb) * scale;
        }
    }
}

// ---------------- logits: one wave per n ----------------
// lane l: head h = l>>3, float4 chunk (l&7). Reduce over 8 lanes.
__global__ __launch_bounds__(256) void logits_kernel(
    const float* __restrict__ q, const float* __restrict__ k,
    const int* __restrict__ rbev, const int* __restrict__ rfeat,
    const int* __restrict__ starts, int N, int ref_num,
    float* __restrict__ Wbuf)
{
    int n = blockIdx.x * 4 + (threadIdx.x >> 6);
    if (n >= N) return;
    int lane = threadIdx.x & 63;
    int f = rfeat[n], b = rbev[n];
    int h = lane >> 3, c = lane & 7;
    float4 qv = *(const float4*)(q + (size_t)b * EMBED + h * HDIM + c * 4);
    float4 kv = *(const float4*)(k + (size_t)f * EMBED + h * HDIM + c * 4);
    float s = qv.x * kv.x + qv.y * kv.y + qv.z * kv.z + qv.w * kv.w;
    s += __shfl_xor(s, 1);
    s += __shfl_xor(s, 2);
    s += __shfl_xor(s, 4);
    if (c == 0) {
        int j = n - starts[f];
        Wbuf[((size_t)f * HEADS + h) * ref_num + j] = s;
    }
}

// ---------------- softmax in place: one wave per (f,h) row ----------------
__global__ __launch_bounds__(256) void softmax_kernel(
    const int* __restrict__ lengths, int ref_num, float* __restrict__ Wbuf)
{
    int idx = blockIdx.x * 4 + (threadIdx.x >> 6); // f*8 + h
    if (idx >= KLEN * HEADS) return;
    int lane = threadIdx.x & 63;
    int len = lengths[idx >> 3];
    float* row = Wbuf + (size_t)idx * ref_num;
    float v = (lane < len) ? row[lane] : -3.0e38f;
    float m = wave_max(v);
    float e = (lane < len) ? __expf(v - m) : 0.f;
    float ssum = wave_sum(e);
    if (lane < ref_num) row[lane] = e / ssum;
}

// ---------------- scatter: one wave per n, atomicAdd into out ----------------
__global__ __launch_bounds__(256) void scatter_kernel(
    const float* __restrict__ v, const float* __restrict__ Wsm,
    const int* __restrict__ rbev, const int* __restrict__ rfeat,
    const int* __restrict__ starts, int N, int ref_num,
    float* __restrict__ out)
{
    int n = blockIdx.x * 4 + (threadIdx.x >> 6);
    if (n >= N) return;
    int lane = threadIdx.x & 63;
    int f = rfeat[n], b = rbev[n];
    int j = n - starts[f];
    int h = lane >> 3, c = lane & 7;
    float wp = Wsm[((size_t)f * HEADS + h) * ref_num + j];
    float4 vv = *(const float4*)(v + (size_t)f * EMBED + h * HDIM + c * 4);
    float* o = out + (size_t)b * EMBED + h * HDIM + c * 4;
    atomicAdd(o + 0, wp * vv.x);
    atomicAdd(o + 1, wp * vv.y);
    atomicAdd(o + 2, wp * vv.z);
    atomicAdd(o + 3, wp * vv.w);
}

// ---------------- layernorm in place: one wave per row ----------------
__global__ __launch_bounds__(256) void ln_kernel(
    float* __restrict__ out, const float* __restrict__ g, const float* __restrict__ b)
{
    int row = blockIdx.x * 4 + (threadIdx.x >> 6);
    if (row >= TGT) return;
    int lane = threadIdx.x & 63;
    float4 x = *(float4*)(out + (size_t)row * EMBED + lane * 4);
    float mu = wave_sum(x.x + x.y + x.z + x.w) * (1.f / EMBED);
    float dx = x.x - mu, dy = x.y - mu, dz = x.z - mu, dw = x.w - mu;
    float var = wave_sum(dx * dx + dy * dy + dz * dz + dw * dw) * (1.f / EMBED);
    float rs = rsqrtf(var + LN_EPS);
    float4 gg = *(const float4*)(g + lane * 4);
    float4 bb = *(const float4*)(b + lane * 4);
    float4 y;
    y.x = dx * rs * gg.x + bb.x;
    y.y = dy * rs * gg.y + bb.y;
    y.z = dz * rs * gg.z + bb.z;
    y.w = dw * rs * gg.w + bb.w;
    *(float4*)(out + (size_t)row * EMBED + lane * 4) = y;
}

extern "C" void kernel_launch(void* const* d_in, const int* in_sizes, int n_in,
                              void* d_out, int out_size, void* d_ws, size_t ws_size,
                              hipStream_t stream) {
    const float* query  = (const float*)d_in[0];
    const float* key_in = (const float*)d_in[1];
    const float* value  = (const float*)d_in[2];
    const int* rfeat    = (const int*)d_in[3];
    const int* rbev     = (const int*)d_in[4];
    const int* starts   = (const int*)d_in[5];
    const int* lengths  = (const int*)d_in[6];
    const float* wq1 = (const float*)d_in[7];
    const float* bq1 = (const float*)d_in[8];
    const float* wq2 = (const float*)d_in[9];
    const float* bq2 = (const float*)d_in[10];
    const float* wk1 = (const float*)d_in[11];
    const float* bk1 = (const float*)d_in[12];
    const float* wk2 = (const float*)d_in[13];
    const float* bk2 = (const float*)d_in[14];
    const float* ln_g = (const float*)d_in[15];
    const float* ln_b = (const float*)d_in[16];

    const int N = in_sizes[3];
    const int rn = (out_size - TGT * EMBED) / (KLEN * HEADS); // ref_num

    float* outp = (float*)d_out;
    float* Wsm  = outp + (size_t)TGT * EMBED;
    float* qbuf = (float*)d_ws;                    // TGT*256 floats
    float* kbuf = qbuf + (size_t)TGT * EMBED;      // KLEN*256 floats

    const float scaling = 0.1767766952966369f; // 32^-0.5

    hipMemsetAsync(outp, 0, (size_t)TGT * EMBED * sizeof(float), stream);

    mlp_kernel<<<TGT / MROWS, 256, 0, stream>>>(query, wq1, bq1, wq2, bq2, scaling, qbuf);
    mlp_kernel<<<KLEN / MROWS, 256, 0, stream>>>(key_in, wk1, bk1, wk2, bk2, 1.0f, kbuf);
    logits_kernel<<<(N + 3) / 4, 256, 0, stream>>>(qbuf, kbuf, rbev, rfeat, starts, N, rn, Wsm);
    softmax_kernel<<<(KLEN * HEADS + 3) / 4, 256, 0, stream>>>(lengths, rn, Wsm);
    scatter_kernel<<<(N + 3) / 4, 256, 0, stream>>>(value, Wsm, rbev, rfeat, starts, N, rn, outp);
    ln_kernel<<<(TGT + 3) / 4, 256, 0, stream>>>(outp, ln_g, ln_b);
}

// Round 2
// 832.082 us; speedup vs baseline: 2.4673x; 2.4673x over previous
//
#include <hip/hip_runtime.h>
#include <math.h>

#define TGT 32400
#define KLEN 16896
#define EMBED 256
#define HEADS 8
#define HDIM 32
#define LN_EPS 1e-5f

// ---------------- wave helpers (wave64) ----------------
__device__ inline float wave_sum(float v) {
#pragma unroll
    for (int o = 32; o; o >>= 1) v += __shfl_xor(v, o);
    return v;
}
__device__ inline float wave_max(float v) {
#pragma unroll
    for (int o = 32; o; o >>= 1) v = fmaxf(v, __shfl_xor(v, o));
    return v;
}
__device__ inline int wave_incl_scan(int v) {
    int lane = threadIdx.x & 63;
#pragma unroll
    for (int o = 1; o < 64; o <<= 1) {
        int x = __shfl_up(v, o);
        if (lane >= o) v += x;
    }
    return v;
}

// ---------------- fused 2-layer MLP ----------------
#define MROWS 16
__global__ __launch_bounds__(256) void mlp_kernel(
    const float* __restrict__ X,
    const float* __restrict__ W1, const float* __restrict__ b1,
    const float* __restrict__ W2, const float* __restrict__ b2,
    float scale, float* __restrict__ Y)
{
    __shared__ float Xs[MROWS][EMBED];     // 16 KiB
    __shared__ float Hs[MROWS][2 * EMBED]; // 32 KiB
    const int t = threadIdx.x;
    const int row0 = blockIdx.x * MROWS;

    {
        const float4* src = (const float4*)(X + (size_t)row0 * EMBED);
        float4* dst = (float4*)(&Xs[0][0]);
#pragma unroll
        for (int i = 0; i < 4; ++i) dst[t + 256 * i] = src[t + 256 * i];
    }
    __syncthreads();

    {
        float acc0[MROWS], acc1[MROWS];
#pragma unroll
        for (int r = 0; r < MROWS; ++r) { acc0[r] = 0.f; acc1[r] = 0.f; }
        for (int k4 = 0; k4 < EMBED / 4; ++k4) {
            float4 xv[MROWS];
#pragma unroll
            for (int r = 0; r < MROWS; ++r) xv[r] = *(const float4*)(&Xs[r][k4 * 4]);
            float w0[4], w1[4];
#pragma unroll
            for (int kk = 0; kk < 4; ++kk) {
                w0[kk] = W1[(size_t)(k4 * 4 + kk) * 512 + t];
                w1[kk] = W1[(size_t)(k4 * 4 + kk) * 512 + t + 256];
            }
#pragma unroll
            for (int r = 0; r < MROWS; ++r) {
                acc0[r] += xv[r].x * w0[0] + xv[r].y * w0[1] + xv[r].z * w0[2] + xv[r].w * w0[3];
                acc1[r] += xv[r].x * w1[0] + xv[r].y * w1[1] + xv[r].z * w1[2] + xv[r].w * w1[3];
            }
        }
        float bb0 = b1[t], bb1 = b1[t + 256];
#pragma unroll
        for (int r = 0; r < MROWS; ++r) {
            Hs[r][t]       = fmaxf(acc0[r] + bb0, 0.f);
            Hs[r][t + 256] = fmaxf(acc1[r] + bb1, 0.f);
        }
    }
    __syncthreads();

    {
        float acc[MROWS];
#pragma unroll
        for (int r = 0; r < MROWS; ++r) acc[r] = 0.f;
        for (int k4 = 0; k4 < 512 / 4; ++k4) {
            float4 hv[MROWS];
#pragma unroll
            for (int r = 0; r < MROWS; ++r) hv[r] = *(const float4*)(&Hs[r][k4 * 4]);
            float w[4];
#pragma unroll
            for (int kk = 0; kk < 4; ++kk) w[kk] = W2[(size_t)(k4 * 4 + kk) * EMBED + t];
#pragma unroll
            for (int r = 0; r < MROWS; ++r) {
                acc[r] += hv[r].x * w[0] + hv[r].y * w[1] + hv[r].z * w[2] + hv[r].w * w[3];
            }
        }
        float bb = b2[t];
#pragma unroll
        for (int r = 0; r < MROWS; ++r) {
            Y[(size_t)(row0 + r) * EMBED + t] = (acc[r] + bb) * scale;
        }
    }
}

// ---------------- logits: one wave per n ----------------
__global__ __launch_bounds__(256) void logits_kernel(
    const float* __restrict__ q, const float* __restrict__ k,
    const int* __restrict__ rbev, const int* __restrict__ rfeat,
    const int* __restrict__ starts, int N, int ref_num,
    float* __restrict__ Wbuf)
{
    int n = blockIdx.x * 4 + (threadIdx.x >> 6);
    if (n >= N) return;
    int lane = threadIdx.x & 63;
    int f = rfeat[n], b = rbev[n];
    int h = lane >> 3, c = lane & 7;
    float4 qv = *(const float4*)(q + (size_t)b * EMBED + h * HDIM + c * 4);
    float4 kv = *(const float4*)(k + (size_t)f * EMBED + h * HDIM + c * 4);
    float s = qv.x * kv.x + qv.y * kv.y + qv.z * kv.z + qv.w * kv.w;
    s += __shfl_xor(s, 1);
    s += __shfl_xor(s, 2);
    s += __shfl_xor(s, 4);
    if (c == 0) {
        int j = n - starts[f];
        Wbuf[((size_t)f * HEADS + h) * ref_num + j] = s;
    }
}

// ---------------- softmax in place: one wave per (f,h) row ----------------
__global__ __launch_bounds__(256) void softmax_kernel(
    const int* __restrict__ lengths, int ref_num, float* __restrict__ Wbuf)
{
    int idx = blockIdx.x * 4 + (threadIdx.x >> 6); // f*8 + h
    if (idx >= KLEN * HEADS) return;
    int lane = threadIdx.x & 63;
    int len = lengths[idx >> 3];
    float* row = Wbuf + (size_t)idx * ref_num;
    float v = (lane < len) ? row[lane] : -3.0e38f;
    float m = wave_max(v);
    float e = (lane < len) ? __expf(v - m) : 0.f;
    float ssum = wave_sum(e);
    if (lane < ref_num) row[lane] = e / ssum;
}

// ---------------- counting sort: histogram ----------------
__global__ __launch_bounds__(256) void hist_kernel(
    const int* __restrict__ rbev, int N, int* __restrict__ count)
{
    int n = blockIdx.x * 256 + threadIdx.x;
    if (n < N) atomicAdd(&count[rbev[n]], 1);
}

// ---------------- single-block exclusive scan over TGT counters ----------------
__global__ __launch_bounds__(1024) void scan_kernel(
    const int* __restrict__ count, int n,
    int* __restrict__ offs, int* __restrict__ cursor)
{
    __shared__ int wsum[16];
    __shared__ int carry_s;
    const int t = threadIdx.x;
    const int lane = t & 63, wid = t >> 6;
    if (t == 0) carry_s = 0;
    __syncthreads();
    for (int base = 0; base < n; base += 1024) {
        int idx = base + t;
        int v = (idx < n) ? count[idx] : 0;
        int incl = wave_incl_scan(v);
        if (lane == 63) wsum[wid] = incl;
        __syncthreads();
        if (wid == 0) {
            int s = (lane < 16) ? wsum[lane] : 0;
            int si = wave_incl_scan(s);
            if (lane < 16) wsum[lane] = si;
        }
        __syncthreads();
        int prefix = (wid > 0) ? wsum[wid - 1] : 0;
        int carry = carry_s;
        int excl = carry + prefix + incl - v;
        if (idx < n) { offs[idx] = excl; cursor[idx] = excl; }
        __syncthreads();
        if (t == 1023) carry_s = carry + prefix + incl;
        __syncthreads();
    }
    if (t == 0) offs[n] = carry_s;
}

// ---------------- permutation fill ----------------
__global__ __launch_bounds__(256) void perm_kernel(
    const int* __restrict__ rbev, int N,
    int* __restrict__ cursor, int* __restrict__ perm)
{
    int n = blockIdx.x * 256 + threadIdx.x;
    if (n < N) {
        int b = rbev[n];
        int pos = atomicAdd(&cursor[b], 1);
        perm[pos] = n;
    }
}

// ---------------- gather + layernorm fused: one wave per output row ----------------
__global__ __launch_bounds__(256) void gather_ln_kernel(
    const float* __restrict__ v, const float* __restrict__ Wsm,
    const int* __restrict__ perm, const int* __restrict__ offs,
    const int* __restrict__ rfeat, const int* __restrict__ starts, int ref_num,
    const float* __restrict__ g, const float* __restrict__ b,
    float* __restrict__ out)
{
    int row = blockIdx.x * 4 + (threadIdx.x >> 6);
    if (row >= TGT) return;
    int lane = threadIdx.x & 63;
    int h = lane >> 3;
    int beg = offs[row], end = offs[row + 1];
    float4 acc = make_float4(0.f, 0.f, 0.f, 0.f);
    for (int i = beg; i < end; ++i) {
        int n = perm[i];
        int f = rfeat[n];
        int j = n - starts[f];
        float wp = Wsm[((size_t)f * HEADS + h) * ref_num + j];
        float4 vv = *(const float4*)(v + (size_t)f * EMBED + lane * 4);
        acc.x += wp * vv.x;
        acc.y += wp * vv.y;
        acc.z += wp * vv.z;
        acc.w += wp * vv.w;
    }
    // layernorm over the 256-wide row held across the wave
    float mu = wave_sum(acc.x + acc.y + acc.z + acc.w) * (1.f / EMBED);
    float dx = acc.x - mu, dy = acc.y - mu, dz = acc.z - mu, dw = acc.w - mu;
    float var = wave_sum(dx * dx + dy * dy + dz * dz + dw * dw) * (1.f / EMBED);
    float rs = rsqrtf(var + LN_EPS);
    float4 gg = *(const float4*)(g + lane * 4);
    float4 bb = *(const float4*)(b + lane * 4);
    float4 y;
    y.x = dx * rs * gg.x + bb.x;
    y.y = dy * rs * gg.y + bb.y;
    y.z = dz * rs * gg.z + bb.z;
    y.w = dw * rs * gg.w + bb.w;
    *(float4*)(out + (size_t)row * EMBED + lane * 4) = y;
}

extern "C" void kernel_launch(void* const* d_in, const int* in_sizes, int n_in,
                              void* d_out, int out_size, void* d_ws, size_t ws_size,
                              hipStream_t stream) {
    const float* query  = (const float*)d_in[0];
    const float* key_in = (const float*)d_in[1];
    const float* value  = (const float*)d_in[2];
    const int* rfeat    = (const int*)d_in[3];
    const int* rbev     = (const int*)d_in[4];
    const int* starts   = (const int*)d_in[5];
    const int* lengths  = (const int*)d_in[6];
    const float* wq1 = (const float*)d_in[7];
    const float* bq1 = (const float*)d_in[8];
    const float* wq2 = (const float*)d_in[9];
    const float* bq2 = (const float*)d_in[10];
    const float* wk1 = (const float*)d_in[11];
    const float* bk1 = (const float*)d_in[12];
    const float* wk2 = (const float*)d_in[13];
    const float* bk2 = (const float*)d_in[14];
    const float* ln_g = (const float*)d_in[15];
    const float* ln_b = (const float*)d_in[16];

    const int N = in_sizes[3];
    const int rn = (out_size - TGT * EMBED) / (KLEN * HEADS); // ref_num

    float* outp = (float*)d_out;
    float* Wsm  = outp + (size_t)TGT * EMBED;

    // workspace layout
    float* qbuf  = (float*)d_ws;                         // TGT*256 f32
    float* kbuf  = qbuf + (size_t)TGT * EMBED;           // KLEN*256 f32
    int* count   = (int*)(kbuf + (size_t)KLEN * EMBED);  // TGT
    int* offs    = count + TGT;                          // TGT+1
    int* cursor  = offs + TGT + 1;                       // TGT
    int* perm    = cursor + TGT;                         // N

    const float scaling = 0.1767766952966369f; // 32^-0.5

    hipMemsetAsync(count, 0, TGT * sizeof(int), stream);

    mlp_kernel<<<TGT / MROWS, 256, 0, stream>>>(query, wq1, bq1, wq2, bq2, scaling, qbuf);
    mlp_kernel<<<KLEN / MROWS, 256, 0, stream>>>(key_in, wk1, bk1, wk2, bk2, 1.0f, kbuf);
    logits_kernel<<<(N + 3) / 4, 256, 0, stream>>>(qbuf, kbuf, rbev, rfeat, starts, N, rn, Wsm);
    softmax_kernel<<<(KLEN * HEADS + 3) / 4, 256, 0, stream>>>(lengths, rn, Wsm);

    hist_kernel<<<(N + 255) / 256, 256, 0, stream>>>(rbev, N, count);
    scan_kernel<<<1, 1024, 0, stream>>>(count, TGT, offs, cursor);
    perm_kernel<<<(N + 255) / 256, 256, 0, stream>>>(rbev, N, cursor, perm);
    gather_ln_kernel<<<(TGT + 3) / 4, 256, 0, stream>>>(value, Wsm, perm, offs,
                                                        rfeat, starts, rn, ln_g, ln_b, outp);
}

// Round 3
// 457.891 us; speedup vs baseline: 4.4836x; 1.8172x over previous
//
#include <hip/hip_runtime.h>
#include <math.h>

#define TGT 32400
#define KLEN 16896
#define EMBED 256
#define HID 512
#define HEADS 8
#define HDIM 32
#define LN_EPS 1e-5f

typedef __attribute__((ext_vector_type(8))) short bf16x8;
typedef __attribute__((ext_vector_type(4))) float f32x4;

__device__ inline short f2bf(float f) {
    union { float f; unsigned u; } v; v.f = f;
    unsigned r = v.u + 0x7FFF + ((v.u >> 16) & 1);
    return (short)(r >> 16);
}

// ---------------- wave helpers (wave64) ----------------
__device__ inline float wave_sum(float v) {
#pragma unroll
    for (int o = 32; o; o >>= 1) v += __shfl_xor(v, o);
    return v;
}
__device__ inline float wave_max(float v) {
#pragma unroll
    for (int o = 32; o; o >>= 1) v = fmaxf(v, __shfl_xor(v, o));
    return v;
}
__device__ inline int wave_incl_scan(int v) {
    int lane = threadIdx.x & 63;
#pragma unroll
    for (int o = 1; o < 64; o <<= 1) {
        int x = __shfl_up(v, o);
        if (lane >= o) v += x;
    }
    return v;
}

// ---------------- weight transpose + bf16 convert ----------------
// W: (R,C) fp32 -> Wt: (C,R) bf16
__global__ __launch_bounds__(256) void wtrans_kernel(
    const float* __restrict__ W, short* __restrict__ Wt, int R, int C)
{
    int i = blockIdx.x * 256 + threadIdx.x;
    if (i < R * C) {
        int c = i / R, r = i - c * R;
        Wt[i] = f2bf(W[(size_t)r * C + c]);
    }
}

// ---------------- MFMA fused 2-layer MLP ----------------
// Y = (relu(X@W1+b1)@W2+b2)*scale. 32 rows/block, 256 threads (4 waves).
// W1t: (512,256) bf16 (transposed W1), W2t: (256,512) bf16.
#define XS_STRIDE 264
#define HS_STRIDE 520
__global__ __launch_bounds__(256) void mlp_mfma_kernel(
    const float* __restrict__ X,
    const short* __restrict__ W1t, const float* __restrict__ b1,
    const short* __restrict__ W2t, const float* __restrict__ b2,
    float scale, int M, float* __restrict__ Y)
{
    __shared__ short Xs[32][XS_STRIDE]; // bf16 bits, padded (stride 528B, 16B-aligned)
    __shared__ short Hs[32][HS_STRIDE]; // bf16 bits, padded (stride 1040B, 16B-aligned)

    const int t = threadIdx.x;
    const int wid = t >> 6;
    const int lane = t & 63;
    const int lrow = lane & 15;   // row/col within 16-tile
    const int kch = lane >> 4;    // k-chunk 0..3
    const int row0 = blockIdx.x * 32;

    // ---- stage X tile (fp32 -> bf16 LDS) ----
#pragma unroll
    for (int i = 0; i < 4; ++i) {
        int chunk = t + 256 * i;          // 1024 chunks of 8 elems
        int r = chunk >> 5;               // 32 chunks per row
        int cc = (chunk & 31) * 8;
        int gr = row0 + r; if (gr > M - 1) gr = M - 1;
        const float4* src = (const float4*)(X + (size_t)gr * EMBED + cc);
        float4 a = src[0], b = src[1];
        bf16x8 pk;
        pk[0] = f2bf(a.x); pk[1] = f2bf(a.y); pk[2] = f2bf(a.z); pk[3] = f2bf(a.w);
        pk[4] = f2bf(b.x); pk[5] = f2bf(b.y); pk[6] = f2bf(b.z); pk[7] = f2bf(b.w);
        *(bf16x8*)(&Xs[r][cc]) = pk;
    }
    __syncthreads();

    // ---- phase 1: H = relu(X@W1 + b1); wave owns cols [128*wid, +128) ----
    {
        f32x4 acc[2][8];
#pragma unroll
        for (int ri = 0; ri < 2; ++ri)
#pragma unroll
            for (int j = 0; j < 8; ++j) acc[ri][j] = (f32x4){0.f, 0.f, 0.f, 0.f};

        for (int ks = 0; ks < 8; ++ks) {
            int k0 = 32 * ks + 8 * kch;
            bf16x8 af0 = *(const bf16x8*)(&Xs[lrow][k0]);
            bf16x8 af1 = *(const bf16x8*)(&Xs[16 + lrow][k0]);
#pragma unroll
            for (int j = 0; j < 8; ++j) {
                int col = 128 * wid + 16 * j + lrow;
                bf16x8 bf = *(const bf16x8*)(W1t + (size_t)col * EMBED + k0);
                acc[0][j] = __builtin_amdgcn_mfma_f32_16x16x32_bf16(af0, bf, acc[0][j], 0, 0, 0);
                acc[1][j] = __builtin_amdgcn_mfma_f32_16x16x32_bf16(af1, bf, acc[1][j], 0, 0, 0);
            }
        }
        // epilogue: bias + relu -> Hs (bf16)
#pragma unroll
        for (int j = 0; j < 8; ++j) {
            int col = 128 * wid + 16 * j + lrow;
            float bb = b1[col];
#pragma unroll
            for (int ri = 0; ri < 2; ++ri) {
#pragma unroll
                for (int rg = 0; rg < 4; ++rg) {
                    int r = 16 * ri + 4 * kch + rg;
                    Hs[r][col] = f2bf(fmaxf(acc[ri][j][rg] + bb, 0.f));
                }
            }
        }
    }
    __syncthreads();

    // ---- phase 2: Y = (H@W2 + b2)*scale; wave owns cols [64*wid, +64) ----
    {
        f32x4 acc[2][4];
#pragma unroll
        for (int ri = 0; ri < 2; ++ri)
#pragma unroll
            for (int j = 0; j < 4; ++j) acc[ri][j] = (f32x4){0.f, 0.f, 0.f, 0.f};

        for (int ks = 0; ks < 16; ++ks) {
            int k0 = 32 * ks + 8 * kch;
            bf16x8 af0 = *(const bf16x8*)(&Hs[lrow][k0]);
            bf16x8 af1 = *(const bf16x8*)(&Hs[16 + lrow][k0]);
#pragma unroll
            for (int j = 0; j < 4; ++j) {
                int col = 64 * wid + 16 * j + lrow;
                bf16x8 bf = *(const bf16x8*)(W2t + (size_t)col * HID + k0);
                acc[0][j] = __builtin_amdgcn_mfma_f32_16x16x32_bf16(af0, bf, acc[0][j], 0, 0, 0);
                acc[1][j] = __builtin_amdgcn_mfma_f32_16x16x32_bf16(af1, bf, acc[1][j], 0, 0, 0);
            }
        }
#pragma unroll
        for (int j = 0; j < 4; ++j) {
            int col = 64 * wid + 16 * j + lrow;
            float bb = b2[col];
#pragma unroll
            for (int ri = 0; ri < 2; ++ri) {
#pragma unroll
                for (int rg = 0; rg < 4; ++rg) {
                    int r = 16 * ri + 4 * kch + rg;
                    int gr = row0 + r;
                    if (gr < M) Y[(size_t)gr * EMBED + col] = (acc[ri][j][rg] + bb) * scale;
                }
            }
        }
    }
}

// ---------------- logits: one wave per n ----------------
__global__ __launch_bounds__(256) void logits_kernel(
    const float* __restrict__ q, const float* __restrict__ k,
    const int* __restrict__ rbev, const int* __restrict__ rfeat,
    const int* __restrict__ starts, int N, int ref_num,
    float* __restrict__ Wbuf)
{
    int n = blockIdx.x * 4 + (threadIdx.x >> 6);
    if (n >= N) return;
    int lane = threadIdx.x & 63;
    int f = rfeat[n], b = rbev[n];
    int h = lane >> 3, c = lane & 7;
    float4 qv = *(const float4*)(q + (size_t)b * EMBED + h * HDIM + c * 4);
    float4 kv = *(const float4*)(k + (size_t)f * EMBED + h * HDIM + c * 4);
    float s = qv.x * kv.x + qv.y * kv.y + qv.z * kv.z + qv.w * kv.w;
    s += __shfl_xor(s, 1);
    s += __shfl_xor(s, 2);
    s += __shfl_xor(s, 4);
    if (c == 0) {
        int j = n - starts[f];
        Wbuf[((size_t)f * HEADS + h) * ref_num + j] = s;
    }
}

// ---------------- softmax in place: one wave per (f,h) row ----------------
__global__ __launch_bounds__(256) void softmax_kernel(
    const int* __restrict__ lengths, int ref_num, float* __restrict__ Wbuf)
{
    int idx = blockIdx.x * 4 + (threadIdx.x >> 6); // f*8 + h
    if (idx >= KLEN * HEADS) return;
    int lane = threadIdx.x & 63;
    int len = lengths[idx >> 3];
    float* row = Wbuf + (size_t)idx * ref_num;
    float v = (lane < len) ? row[lane] : -3.0e38f;
    float m = wave_max(v);
    float e = (lane < len) ? __expf(v - m) : 0.f;
    float ssum = wave_sum(e);
    if (lane < ref_num) row[lane] = e / ssum;
}

// ---------------- counting sort: histogram ----------------
__global__ __launch_bounds__(256) void hist_kernel(
    const int* __restrict__ rbev, int N, int* __restrict__ count)
{
    int n = blockIdx.x * 256 + threadIdx.x;
    if (n < N) atomicAdd(&count[rbev[n]], 1);
}

// ---------------- single-block exclusive scan over TGT counters ----------------
__global__ __launch_bounds__(1024) void scan_kernel(
    const int* __restrict__ count, int n,
    int* __restrict__ offs, int* __restrict__ cursor)
{
    __shared__ int wsum[16];
    __shared__ int carry_s;
    const int t = threadIdx.x;
    const int lane = t & 63, wid = t >> 6;
    if (t == 0) carry_s = 0;
    __syncthreads();
    for (int base = 0; base < n; base += 1024) {
        int idx = base + t;
        int v = (idx < n) ? count[idx] : 0;
        int incl = wave_incl_scan(v);
        if (lane == 63) wsum[wid] = incl;
        __syncthreads();
        if (wid == 0) {
            int s = (lane < 16) ? wsum[lane] : 0;
            int si = wave_incl_scan(s);
            if (lane < 16) wsum[lane] = si;
        }
        __syncthreads();
        int prefix = (wid > 0) ? wsum[wid - 1] : 0;
        int carry = carry_s;
        int excl = carry + prefix + incl - v;
        if (idx < n) { offs[idx] = excl; cursor[idx] = excl; }
        __syncthreads();
        if (t == 1023) carry_s = carry + prefix + incl;
        __syncthreads();
    }
    if (t == 0) offs[n] = carry_s;
}

// ---------------- permutation fill ----------------
__global__ __launch_bounds__(256) void perm_kernel(
    const int* __restrict__ rbev, int N,
    int* __restrict__ cursor, int* __restrict__ perm)
{
    int n = blockIdx.x * 256 + threadIdx.x;
    if (n < N) {
        int b = rbev[n];
        int pos = atomicAdd(&cursor[b], 1);
        perm[pos] = n;
    }
}

// ---------------- gather + layernorm fused: one wave per output row ----------------
__global__ __launch_bounds__(256) void gather_ln_kernel(
    const float* __restrict__ v, const float* __restrict__ Wsm,
    const int* __restrict__ perm, const int* __restrict__ offs,
    const int* __restrict__ rfeat, const int* __restrict__ starts, int ref_num,
    const float* __restrict__ g, const float* __restrict__ b,
    float* __restrict__ out)
{
    int row = blockIdx.x * 4 + (threadIdx.x >> 6);
    if (row >= TGT) return;
    int lane = threadIdx.x & 63;
    int h = lane >> 3;
    int beg = offs[row], end = offs[row + 1];
    float4 acc = make_float4(0.f, 0.f, 0.f, 0.f);
    for (int i = beg; i < end; ++i) {
        int n = perm[i];
        int f = rfeat[n];
        int j = n - starts[f];
        float wp = Wsm[((size_t)f * HEADS + h) * ref_num + j];
        float4 vv = *(const float4*)(v + (size_t)f * EMBED + lane * 4);
        acc.x += wp * vv.x;
        acc.y += wp * vv.y;
        acc.z += wp * vv.z;
        acc.w += wp * vv.w;
    }
    float mu = wave_sum(acc.x + acc.y + acc.z + acc.w) * (1.f / EMBED);
    float dx = acc.x - mu, dy = acc.y - mu, dz = acc.z - mu, dw = acc.w - mu;
    float var = wave_sum(dx * dx + dy * dy + dz * dz + dw * dw) * (1.f / EMBED);
    float rs = rsqrtf(var + LN_EPS);
    float4 gg = *(const float4*)(g + lane * 4);
    float4 bb = *(const float4*)(b + lane * 4);
    float4 y;
    y.x = dx * rs * gg.x + bb.x;
    y.y = dy * rs * gg.y + bb.y;
    y.z = dz * rs * gg.z + bb.z;
    y.w = dw * rs * gg.w + bb.w;
    *(float4*)(out + (size_t)row * EMBED + lane * 4) = y;
}

extern "C" void kernel_launch(void* const* d_in, const int* in_sizes, int n_in,
                              void* d_out, int out_size, void* d_ws, size_t ws_size,
                              hipStream_t stream) {
    const float* query  = (const float*)d_in[0];
    const float* key_in = (const float*)d_in[1];
    const float* value  = (const float*)d_in[2];
    const int* rfeat    = (const int*)d_in[3];
    const int* rbev     = (const int*)d_in[4];
    const int* starts   = (const int*)d_in[5];
    const int* lengths  = (const int*)d_in[6];
    const float* wq1 = (const float*)d_in[7];
    const float* bq1 = (const float*)d_in[8];
    const float* wq2 = (const float*)d_in[9];
    const float* bq2 = (const float*)d_in[10];
    const float* wk1 = (const float*)d_in[11];
    const float* bk1 = (const float*)d_in[12];
    const float* wk2 = (const float*)d_in[13];
    const float* bk2 = (const float*)d_in[14];
    const float* ln_g = (const float*)d_in[15];
    const float* ln_b = (const float*)d_in[16];

    const int N = in_sizes[3];
    const int rn = (out_size - TGT * EMBED) / (KLEN * HEADS); // ref_num

    float* outp = (float*)d_out;
    float* Wsm  = outp + (size_t)TGT * EMBED;

    // workspace layout
    float* qbuf  = (float*)d_ws;                         // TGT*256 f32
    float* kbuf  = qbuf + (size_t)TGT * EMBED;           // KLEN*256 f32
    int* count   = (int*)(kbuf + (size_t)KLEN * EMBED);  // TGT
    int* offs    = count + TGT;                          // TGT+1
    int* cursor  = offs + TGT + 1;                       // TGT
    int* perm    = cursor + TGT;                         // N
    short* Wq1t  = (short*)(perm + N);                   // 512*256 bf16
    short* Wq2t  = Wq1t + EMBED * HID;                   // 256*512
    short* Wk1t  = Wq2t + EMBED * HID;
    short* Wk2t  = Wk1t + EMBED * HID;

    const float scaling = 0.1767766952966369f; // 32^-0.5

    hipMemsetAsync(count, 0, TGT * sizeof(int), stream);

    // transpose+convert weights (tiny)
    wtrans_kernel<<<(EMBED * HID + 255) / 256, 256, 0, stream>>>(wq1, Wq1t, EMBED, HID);
    wtrans_kernel<<<(EMBED * HID + 255) / 256, 256, 0, stream>>>(wq2, Wq2t, HID, EMBED);
    wtrans_kernel<<<(EMBED * HID + 255) / 256, 256, 0, stream>>>(wk1, Wk1t, EMBED, HID);
    wtrans_kernel<<<(EMBED * HID + 255) / 256, 256, 0, stream>>>(wk2, Wk2t, HID, EMBED);

    mlp_mfma_kernel<<<(TGT + 31) / 32, 256, 0, stream>>>(query, Wq1t, bq1, Wq2t, bq2, scaling, TGT, qbuf);
    mlp_mfma_kernel<<<(KLEN + 31) / 32, 256, 0, stream>>>(key_in, Wk1t, bk1, Wk2t, bk2, 1.0f, KLEN, kbuf);

    logits_kernel<<<(N + 3) / 4, 256, 0, stream>>>(qbuf, kbuf, rbev, rfeat, starts, N, rn, Wsm);
    softmax_kernel<<<(KLEN * HEADS + 3) / 4, 256, 0, stream>>>(lengths, rn, Wsm);

    hist_kernel<<<(N + 255) / 256, 256, 0, stream>>>(rbev, N, count);
    scan_kernel<<<1, 1024, 0, stream>>>(count, TGT, offs, cursor);
    perm_kernel<<<(N + 255) / 256, 256, 0, stream>>>(rbev, N, cursor, perm);
    gather_ln_kernel<<<(TGT + 3) / 4, 256, 0, stream>>>(value, Wsm, perm, offs,
                                                        rfeat, starts, rn, ln_g, ln_b, outp);
}

// Round 4
// 361.891 us; speedup vs baseline: 5.6730x; 1.2653x over previous
//
#include <hip/hip_runtime.h>
#include <math.h>

#define TGT 32400
#define KLEN 16896
#define EMBED 256
#define HID 512
#define HEADS 8
#define HDIM 32
#define LN_EPS 1e-5f

typedef __attribute__((ext_vector_type(8))) short bf16x8;
typedef __attribute__((ext_vector_type(4))) short bf16x4;
typedef __attribute__((ext_vector_type(4))) float f32x4;

__device__ inline short f2bf(float f) {
    union { float f; unsigned u; } v; v.f = f;
    unsigned r = v.u + 0x7FFF + ((v.u >> 16) & 1);
    return (short)(r >> 16);
}
__device__ inline float bf2f(short s) {
    union { unsigned u; float f; } v;
    v.u = ((unsigned)(unsigned short)s) << 16;
    return v.f;
}

// ---------------- wave helpers (wave64) ----------------
__device__ inline float wave_sum(float v) {
#pragma unroll
    for (int o = 32; o; o >>= 1) v += __shfl_xor(v, o);
    return v;
}
__device__ inline int wave_incl_scan(int v) {
    int lane = threadIdx.x & 63;
#pragma unroll
    for (int o = 1; o < 64; o <<= 1) {
        int x = __shfl_up(v, o);
        if (lane >= o) v += x;
    }
    return v;
}

// ---------------- prep: 4x weight transpose->bf16, value->bf16, histogram ----------------
// block layout: [0,2112): vconv  [2112,4160): wtrans  [4160,...): hist
__global__ __launch_bounds__(256) void prep_kernel(
    const float* __restrict__ value, short* __restrict__ vbf,
    const float* __restrict__ wq1, const float* __restrict__ wq2,
    const float* __restrict__ wk1, const float* __restrict__ wk2,
    short* __restrict__ Wt,   // 4 matrices contiguous, 131072 bf16 each
    const int* __restrict__ rbev, int N, int* __restrict__ count)
{
    int bid = blockIdx.x;
    if (bid < 2112) {
        int idx = bid * 256 + threadIdx.x;   // 540672 chunks of 8
        const float4* s4 = (const float4*)value + (size_t)idx * 2;
        float4 a = s4[0], b = s4[1];
        bf16x8 pk;
        pk[0] = f2bf(a.x); pk[1] = f2bf(a.y); pk[2] = f2bf(a.z); pk[3] = f2bf(a.w);
        pk[4] = f2bf(b.x); pk[5] = f2bf(b.y); pk[6] = f2bf(b.z); pk[7] = f2bf(b.w);
        *(bf16x8*)(vbf + (size_t)idx * 8) = pk;
    } else if (bid < 4160) {
        int i = (bid - 2112) * 256 + threadIdx.x;  // 0..524287
        int m = i >> 17;                           // which matrix
        int r17 = i & 131071;
        int shift = 8 + (m & 1);                   // R = 256 or 512
        int C = 131072 >> shift;
        int r = r17 & ((1 << shift) - 1);
        int c = r17 >> shift;
        const float* W = (m == 0) ? wq1 : (m == 1) ? wq2 : (m == 2) ? wk1 : wk2;
        Wt[(size_t)m * 131072 + r17] = f2bf(W[(size_t)r * C + c]);
    } else {
        int n = (bid - 4160) * 256 + threadIdx.x;
        if (n < N) atomicAdd(&count[rbev[n]], 1);
    }
}

// ---------------- MFMA fused 2-layer MLP (bf16 out) ----------------
#define XS_STRIDE 264
#define HS_STRIDE 520
__global__ __launch_bounds__(256) void mlp_mfma_kernel(
    const float* __restrict__ X,
    const short* __restrict__ W1t, const float* __restrict__ b1,
    const short* __restrict__ W2t, const float* __restrict__ b2,
    float scale, int M, short* __restrict__ Y)
{
    __shared__ short Xs[32][XS_STRIDE];
    __shared__ short Hs[32][HS_STRIDE];

    const int t = threadIdx.x;
    const int wid = t >> 6;
    const int lane = t & 63;
    const int lrow = lane & 15;
    const int kch = lane >> 4;
    const int row0 = blockIdx.x * 32;

#pragma unroll
    for (int i = 0; i < 4; ++i) {
        int chunk = t + 256 * i;
        int r = chunk >> 5;
        int cc = (chunk & 31) * 8;
        int gr = row0 + r; if (gr > M - 1) gr = M - 1;
        const float4* src = (const float4*)(X + (size_t)gr * EMBED + cc);
        float4 a = src[0], b = src[1];
        bf16x8 pk;
        pk[0] = f2bf(a.x); pk[1] = f2bf(a.y); pk[2] = f2bf(a.z); pk[3] = f2bf(a.w);
        pk[4] = f2bf(b.x); pk[5] = f2bf(b.y); pk[6] = f2bf(b.z); pk[7] = f2bf(b.w);
        *(bf16x8*)(&Xs[r][cc]) = pk;
    }
    __syncthreads();

    {
        f32x4 acc[2][8];
#pragma unroll
        for (int ri = 0; ri < 2; ++ri)
#pragma unroll
            for (int j = 0; j < 8; ++j) acc[ri][j] = (f32x4){0.f, 0.f, 0.f, 0.f};

        for (int ks = 0; ks < 8; ++ks) {
            int k0 = 32 * ks + 8 * kch;
            bf16x8 af0 = *(const bf16x8*)(&Xs[lrow][k0]);
            bf16x8 af1 = *(const bf16x8*)(&Xs[16 + lrow][k0]);
#pragma unroll
            for (int j = 0; j < 8; ++j) {
                int col = 128 * wid + 16 * j + lrow;
                bf16x8 bf = *(const bf16x8*)(W1t + (size_t)col * EMBED + k0);
                acc[0][j] = __builtin_amdgcn_mfma_f32_16x16x32_bf16(af0, bf, acc[0][j], 0, 0, 0);
                acc[1][j] = __builtin_amdgcn_mfma_f32_16x16x32_bf16(af1, bf, acc[1][j], 0, 0, 0);
            }
        }
#pragma unroll
        for (int j = 0; j < 8; ++j) {
            int col = 128 * wid + 16 * j + lrow;
            float bb = b1[col];
#pragma unroll
            for (int ri = 0; ri < 2; ++ri) {
#pragma unroll
                for (int rg = 0; rg < 4; ++rg) {
                    int r = 16 * ri + 4 * kch + rg;
                    Hs[r][col] = f2bf(fmaxf(acc[ri][j][rg] + bb, 0.f));
                }
            }
        }
    }
    __syncthreads();

    {
        f32x4 acc[2][4];
#pragma unroll
        for (int ri = 0; ri < 2; ++ri)
#pragma unroll
            for (int j = 0; j < 4; ++j) acc[ri][j] = (f32x4){0.f, 0.f, 0.f, 0.f};

        for (int ks = 0; ks < 16; ++ks) {
            int k0 = 32 * ks + 8 * kch;
            bf16x8 af0 = *(const bf16x8*)(&Hs[lrow][k0]);
            bf16x8 af1 = *(const bf16x8*)(&Hs[16 + lrow][k0]);
#pragma unroll
            for (int j = 0; j < 4; ++j) {
                int col = 64 * wid + 16 * j + lrow;
                bf16x8 bf = *(const bf16x8*)(W2t + (size_t)col * HID + k0);
                acc[0][j] = __builtin_amdgcn_mfma_f32_16x16x32_bf16(af0, bf, acc[0][j], 0, 0, 0);
                acc[1][j] = __builtin_amdgcn_mfma_f32_16x16x32_bf16(af1, bf, acc[1][j], 0, 0, 0);
            }
        }
#pragma unroll
        for (int j = 0; j < 4; ++j) {
            int col = 64 * wid + 16 * j + lrow;
            float bb = b2[col];
#pragma unroll
            for (int ri = 0; ri < 2; ++ri) {
#pragma unroll
                for (int rg = 0; rg < 4; ++rg) {
                    int r = 16 * ri + 4 * kch + rg;
                    int gr = row0 + r;
                    if (gr < M) Y[(size_t)gr * EMBED + col] = f2bf((acc[ri][j][rg] + bb) * scale);
                }
            }
        }
    }
}

// ---------------- fused logits + softmax: one wave per feature ----------------
__global__ __launch_bounds__(256) void logits_sm_kernel(
    const short* __restrict__ q, const short* __restrict__ k,
    const int* __restrict__ rbev, const int* __restrict__ starts,
    const int* __restrict__ lengths, int ref_num,
    float* __restrict__ Wsm)
{
    __shared__ float Ll[4][HEADS][48];
    int f = blockIdx.x * 4 + (threadIdx.x >> 6);
    if (f >= KLEN) return;
    int w = threadIdx.x >> 6;
    int lane = threadIdx.x & 63;
    int h = lane >> 3, c = lane & 7;
    int st = starts[f], len = lengths[f];

    // k slice (8B per lane, contiguous across wave)
    bf16x4 kv = *(const bf16x4*)(k + (size_t)f * EMBED + lane * 4);
    float k0 = bf2f(kv[0]), k1 = bf2f(kv[1]), k2 = bf2f(kv[2]), k3 = bf2f(kv[3]);

    for (int j = 0; j < len; ++j) {
        int b = rbev[st + j];
        bf16x4 qv = *(const bf16x4*)(q + (size_t)b * EMBED + lane * 4);
        float s = bf2f(qv[0]) * k0 + bf2f(qv[1]) * k1 + bf2f(qv[2]) * k2 + bf2f(qv[3]) * k3;
        s += __shfl_xor(s, 1);
        s += __shfl_xor(s, 2);
        s += __shfl_xor(s, 4);
        if (c == 0) Ll[w][h][j] = s;
    }
    asm volatile("" ::: "memory"); // wave-lockstep LDS: block compiler reordering

    // per-head softmax: 8-lane group, lane covers j = c, c+8, ...
    float m = -3.0e38f;
    for (int j = c; j < len; j += 8) m = fmaxf(m, Ll[w][h][j]);
    m = fmaxf(m, __shfl_xor(m, 1));
    m = fmaxf(m, __shfl_xor(m, 2));
    m = fmaxf(m, __shfl_xor(m, 4));
    float sum = 0.f;
    for (int j = c; j < len; j += 8) {
        float e = __expf(Ll[w][h][j] - m);
        Ll[w][h][j] = e;
        sum += e;
    }
    sum += __shfl_xor(sum, 1);
    sum += __shfl_xor(sum, 2);
    sum += __shfl_xor(sum, 4);
    float inv = 1.f / sum;
    float* row = Wsm + ((size_t)f * HEADS + h) * ref_num;
    for (int j = c; j < ref_num; j += 8) {
        row[j] = (j < len) ? Ll[w][h][j] * inv : 0.f;
    }
}

// ---------------- single-block exclusive scan over TGT counters ----------------
__global__ __launch_bounds__(1024) void scan_kernel(
    const int* __restrict__ count, int n,
    int* __restrict__ offs, int* __restrict__ cursor)
{
    __shared__ int wsum[16];
    __shared__ int carry_s;
    const int t = threadIdx.x;
    const int lane = t & 63, wid = t >> 6;
    if (t == 0) carry_s = 0;
    __syncthreads();
    for (int base = 0; base < n; base += 1024) {
        int idx = base + t;
        int v = (idx < n) ? count[idx] : 0;
        int incl = wave_incl_scan(v);
        if (lane == 63) wsum[wid] = incl;
        __syncthreads();
        if (wid == 0) {
            int s = (lane < 16) ? wsum[lane] : 0;
            int si = wave_incl_scan(s);
            if (lane < 16) wsum[lane] = si;
        }
        __syncthreads();
        int prefix = (wid > 0) ? wsum[wid - 1] : 0;
        int carry = carry_s;
        int excl = carry + prefix + incl - v;
        if (idx < n) { offs[idx] = excl; cursor[idx] = excl; }
        __syncthreads();
        if (t == 1023) carry_s = carry + prefix + incl;
        __syncthreads();
    }
    if (t == 0) offs[n] = carry_s;
}

// ---------------- permutation fill: pack (f,j) ----------------
__global__ __launch_bounds__(256) void perm_kernel(
    const int* __restrict__ rbev, const int* __restrict__ rfeat,
    const int* __restrict__ starts, int N,
    int* __restrict__ cursor, int* __restrict__ perm)
{
    int n = blockIdx.x * 256 + threadIdx.x;
    if (n < N) {
        int b = rbev[n];
        int f = rfeat[n];
        int j = n - starts[f];
        int pos = atomicAdd(&cursor[b], 1);
        perm[pos] = (f << 6) | j;
    }
}

// ---------------- gather + layernorm fused: one wave per output row ----------------
__global__ __launch_bounds__(256) void gather_ln_kernel(
    const short* __restrict__ vbf, const float* __restrict__ Wsm,
    const int* __restrict__ perm, const int* __restrict__ offs, int ref_num,
    const float* __restrict__ g, const float* __restrict__ b,
    float* __restrict__ out)
{
    int row = blockIdx.x * 4 + (threadIdx.x >> 6);
    if (row >= TGT) return;
    int lane = threadIdx.x & 63;
    int h = lane >> 3;
    int beg = offs[row], end = offs[row + 1];
    float4 acc = make_float4(0.f, 0.f, 0.f, 0.f);
    for (int i = beg; i < end; ++i) {
        int pk = perm[i];
        int f = pk >> 6, j = pk & 63;
        float wp = Wsm[((size_t)f * HEADS + h) * ref_num + j];
        bf16x4 vv = *(const bf16x4*)(vbf + (size_t)f * EMBED + lane * 4);
        acc.x += wp * bf2f(vv[0]);
        acc.y += wp * bf2f(vv[1]);
        acc.z += wp * bf2f(vv[2]);
        acc.w += wp * bf2f(vv[3]);
    }
    float mu = wave_sum(acc.x + acc.y + acc.z + acc.w) * (1.f / EMBED);
    float dx = acc.x - mu, dy = acc.y - mu, dz = acc.z - mu, dw = acc.w - mu;
    float var = wave_sum(dx * dx + dy * dy + dz * dz + dw * dw) * (1.f / EMBED);
    float rs = rsqrtf(var + LN_EPS);
    float4 gg = *(const float4*)(g + lane * 4);
    float4 bb = *(const float4*)(b + lane * 4);
    float4 y;
    y.x = dx * rs * gg.x + bb.x;
    y.y = dy * rs * gg.y + bb.y;
    y.z = dz * rs * gg.z + bb.z;
    y.w = dw * rs * gg.w + bb.w;
    *(float4*)(out + (size_t)row * EMBED + lane * 4) = y;
}

extern "C" void kernel_launch(void* const* d_in, const int* in_sizes, int n_in,
                              void* d_out, int out_size, void* d_ws, size_t ws_size,
                              hipStream_t stream) {
    const float* query  = (const float*)d_in[0];
    const float* key_in = (const float*)d_in[1];
    const float* value  = (const float*)d_in[2];
    const int* rfeat    = (const int*)d_in[3];
    const int* rbev     = (const int*)d_in[4];
    const int* starts   = (const int*)d_in[5];
    const int* lengths  = (const int*)d_in[6];
    const float* wq1 = (const float*)d_in[7];
    const float* bq1 = (const float*)d_in[8];
    const float* wq2 = (const float*)d_in[9];
    const float* bq2 = (const float*)d_in[10];
    const float* wk1 = (const float*)d_in[11];
    const float* bk1 = (const float*)d_in[12];
    const float* wk2 = (const float*)d_in[13];
    const float* bk2 = (const float*)d_in[14];
    const float* ln_g = (const float*)d_in[15];
    const float* ln_b = (const float*)d_in[16];

    const int N = in_sizes[3];
    const int rn = (out_size - TGT * EMBED) / (KLEN * HEADS); // ref_num

    float* outp = (float*)d_out;
    float* Wsm  = outp + (size_t)TGT * EMBED;

    // workspace layout (bf16 where possible)
    short* qbuf = (short*)d_ws;                          // TGT*256 bf16
    short* kbuf = qbuf + (size_t)TGT * EMBED;            // KLEN*256 bf16
    short* vbf  = kbuf + (size_t)KLEN * EMBED;           // KLEN*256 bf16
    int* count  = (int*)(vbf + (size_t)KLEN * EMBED);    // TGT
    int* offs   = count + TGT;                           // TGT+1
    int* cursor = offs + TGT + 1;                        // TGT
    int* perm   = cursor + TGT;                          // N
    short* Wt   = (short*)(perm + N);                    // 4*131072 bf16
    short* Wq1t = Wt;
    short* Wq2t = Wt + 131072;
    short* Wk1t = Wt + 2 * 131072;
    short* Wk2t = Wt + 3 * 131072;

    const float scaling = 0.1767766952966369f; // 32^-0.5

    hipMemsetAsync(count, 0, TGT * sizeof(int), stream);

    int hist_blocks = (N + 255) / 256;
    prep_kernel<<<4160 + hist_blocks, 256, 0, stream>>>(
        value, vbf, wq1, wq2, wk1, wk2, Wt, rbev, N, count);

    mlp_mfma_kernel<<<(TGT + 31) / 32, 256, 0, stream>>>(query, Wq1t, bq1, Wq2t, bq2, scaling, TGT, qbuf);
    mlp_mfma_kernel<<<(KLEN + 31) / 32, 256, 0, stream>>>(key_in, Wk1t, bk1, Wk2t, bk2, 1.0f, KLEN, kbuf);

    logits_sm_kernel<<<(KLEN + 3) / 4, 256, 0, stream>>>(qbuf, kbuf, rbev, starts, lengths, rn, Wsm);

    scan_kernel<<<1, 1024, 0, stream>>>(count, TGT, offs, cursor);
    perm_kernel<<<(N + 255) / 256, 256, 0, stream>>>(rbev, rfeat, starts, N, cursor, perm);
    gather_ln_kernel<<<(TGT + 3) / 4, 256, 0, stream>>>(vbf, Wsm, perm, offs, rn, ln_g, ln_b, outp);
}

// Round 5
// 321.918 us; speedup vs baseline: 6.3774x; 1.1242x over previous
//
#include <hip/hip_runtime.h>
#include <math.h>

#define TGT 32400
#define KLEN 16896
#define EMBED 256
#define HID 512
#define HEADS 8
#define HDIM 32
#define LN_EPS 1e-5f

typedef __attribute__((ext_vector_type(8))) short bf16x8;
typedef __attribute__((ext_vector_type(4))) short bf16x4;
typedef __attribute__((ext_vector_type(4))) float f32x4;

__device__ inline short f2bf(float f) {
    union { float f; unsigned u; } v; v.f = f;
    unsigned r = v.u + 0x7FFF + ((v.u >> 16) & 1);
    return (short)(r >> 16);
}
__device__ inline float bf2f(short s) {
    union { unsigned u; float f; } v;
    v.u = ((unsigned)(unsigned short)s) << 16;
    return v.f;
}

// ---------------- wave helpers (wave64) ----------------
__device__ inline float wave_sum(float v) {
#pragma unroll
    for (int o = 32; o; o >>= 1) v += __shfl_xor(v, o);
    return v;
}
__device__ inline int wave_incl_scan(int v) {
    int lane = threadIdx.x & 63;
#pragma unroll
    for (int o = 1; o < 64; o <<= 1) {
        int x = __shfl_up(v, o);
        if (lane >= o) v += x;
    }
    return v;
}

// ---------------- prep: 4x weight transpose->bf16, value->bf16, histogram ----------------
__global__ __launch_bounds__(256) void prep_kernel(
    const float* __restrict__ value, short* __restrict__ vbf,
    const float* __restrict__ wq1, const float* __restrict__ wq2,
    const float* __restrict__ wk1, const float* __restrict__ wk2,
    short* __restrict__ Wt,
    const int* __restrict__ rbev, int N, int* __restrict__ count)
{
    int bid = blockIdx.x;
    if (bid < 2112) {
        int idx = bid * 256 + threadIdx.x;
        const float4* s4 = (const float4*)value + (size_t)idx * 2;
        float4 a = s4[0], b = s4[1];
        bf16x8 pk;
        pk[0] = f2bf(a.x); pk[1] = f2bf(a.y); pk[2] = f2bf(a.z); pk[3] = f2bf(a.w);
        pk[4] = f2bf(b.x); pk[5] = f2bf(b.y); pk[6] = f2bf(b.z); pk[7] = f2bf(b.w);
        *(bf16x8*)(vbf + (size_t)idx * 8) = pk;
    } else if (bid < 4160) {
        int i = (bid - 2112) * 256 + threadIdx.x;
        int m = i >> 17;
        int r17 = i & 131071;
        int shift = 8 + (m & 1);
        int C = 131072 >> shift;
        int r = r17 & ((1 << shift) - 1);
        int c = r17 >> shift;
        const float* W = (m == 0) ? wq1 : (m == 1) ? wq2 : (m == 2) ? wk1 : wk2;
        Wt[(size_t)m * 131072 + r17] = f2bf(W[(size_t)r * C + c]);
    } else {
        int n = (bid - 4160) * 256 + threadIdx.x;
        if (n < N) atomicAdd(&count[rbev[n]], 1);
    }
}

// ---------------- MFMA fused 2-layer MLP, Q and K merged, 8 waves/block ----------------
#define XS_STRIDE 264
#define HS_STRIDE 520
__global__ __launch_bounds__(512) void mlp_mfma_kernel(
    const float* __restrict__ Xq, const float* __restrict__ Xk, int nQblk,
    const short* __restrict__ Wt,  // [Wq1t, Wq2t, Wk1t, Wk2t] x 131072
    const float* __restrict__ bq1, const float* __restrict__ bq2,
    const float* __restrict__ bk1, const float* __restrict__ bk2,
    float scaleQ,
    short* __restrict__ Yq, short* __restrict__ Yk)
{
    __shared__ short Xs[32][XS_STRIDE];
    __shared__ short Hs[32][HS_STRIDE];

    const bool isQ = (int)blockIdx.x < nQblk;
    const int blk = isQ ? blockIdx.x : blockIdx.x - nQblk;
    const int M = isQ ? TGT : KLEN;
    const float* X = isQ ? Xq : Xk;
    const short* W1t = Wt + (isQ ? 0 : 2) * 131072;
    const short* W2t = Wt + (isQ ? 1 : 3) * 131072;
    const float* b1 = isQ ? bq1 : bk1;
    const float* b2 = isQ ? bq2 : bk2;
    const float scale = isQ ? scaleQ : 1.0f;
    short* Y = isQ ? Yq : Yk;

    const int t = threadIdx.x;
    const int wid = t >> 6;      // 0..7
    const int lane = t & 63;
    const int lrow = lane & 15;
    const int kch = lane >> 4;
    const int row0 = blk * 32;

    // ---- stage X tile (fp32 -> bf16 LDS) ----
#pragma unroll
    for (int i = 0; i < 2; ++i) {
        int chunk = t + 512 * i;
        int r = chunk >> 5;
        int cc = (chunk & 31) * 8;
        int gr = row0 + r; if (gr > M - 1) gr = M - 1;
        const float4* src = (const float4*)(X + (size_t)gr * EMBED + cc);
        float4 a = src[0], b = src[1];
        bf16x8 pk;
        pk[0] = f2bf(a.x); pk[1] = f2bf(a.y); pk[2] = f2bf(a.z); pk[3] = f2bf(a.w);
        pk[4] = f2bf(b.x); pk[5] = f2bf(b.y); pk[6] = f2bf(b.z); pk[7] = f2bf(b.w);
        *(bf16x8*)(&Xs[r][cc]) = pk;
    }
    __syncthreads();

    // ---- phase 1: H = relu(X@W1 + b1); wave owns 64 cols ----
    {
        f32x4 acc[2][4];
#pragma unroll
        for (int ri = 0; ri < 2; ++ri)
#pragma unroll
            for (int j = 0; j < 4; ++j) acc[ri][j] = (f32x4){0.f, 0.f, 0.f, 0.f};

        for (int ks = 0; ks < 8; ++ks) {
            int k0 = 32 * ks + 8 * kch;
            bf16x8 af0 = *(const bf16x8*)(&Xs[lrow][k0]);
            bf16x8 af1 = *(const bf16x8*)(&Xs[16 + lrow][k0]);
#pragma unroll
            for (int j = 0; j < 4; ++j) {
                int col = 64 * wid + 16 * j + lrow;
                bf16x8 bf = *(const bf16x8*)(W1t + (size_t)col * EMBED + k0);
                acc[0][j] = __builtin_amdgcn_mfma_f32_16x16x32_bf16(af0, bf, acc[0][j], 0, 0, 0);
                acc[1][j] = __builtin_amdgcn_mfma_f32_16x16x32_bf16(af1, bf, acc[1][j], 0, 0, 0);
            }
        }
#pragma unroll
        for (int j = 0; j < 4; ++j) {
            int col = 64 * wid + 16 * j + lrow;
            float bb = b1[col];
#pragma unroll
            for (int ri = 0; ri < 2; ++ri) {
#pragma unroll
                for (int rg = 0; rg < 4; ++rg) {
                    int r = 16 * ri + 4 * kch + rg;
                    Hs[r][col] = f2bf(fmaxf(acc[ri][j][rg] + bb, 0.f));
                }
            }
        }
    }
    __syncthreads();

    // ---- phase 2: Y = (H@W2 + b2)*scale; wave owns 32 cols ----
    {
        f32x4 acc[2][2];
#pragma unroll
        for (int ri = 0; ri < 2; ++ri)
#pragma unroll
            for (int j = 0; j < 2; ++j) acc[ri][j] = (f32x4){0.f, 0.f, 0.f, 0.f};

        for (int ks = 0; ks < 16; ++ks) {
            int k0 = 32 * ks + 8 * kch;
            bf16x8 af0 = *(const bf16x8*)(&Hs[lrow][k0]);
            bf16x8 af1 = *(const bf16x8*)(&Hs[16 + lrow][k0]);
#pragma unroll
            for (int j = 0; j < 2; ++j) {
                int col = 32 * wid + 16 * j + lrow;
                bf16x8 bf = *(const bf16x8*)(W2t + (size_t)col * HID + k0);
                acc[0][j] = __builtin_amdgcn_mfma_f32_16x16x32_bf16(af0, bf, acc[0][j], 0, 0, 0);
                acc[1][j] = __builtin_amdgcn_mfma_f32_16x16x32_bf16(af1, bf, acc[1][j], 0, 0, 0);
            }
        }
#pragma unroll
        for (int j = 0; j < 2; ++j) {
            int col = 32 * wid + 16 * j + lrow;
            float bb = b2[col];
#pragma unroll
            for (int ri = 0; ri < 2; ++ri) {
#pragma unroll
                for (int rg = 0; rg < 4; ++rg) {
                    int r = 16 * ri + 4 * kch + rg;
                    int gr = row0 + r;
                    if (gr < M) Y[(size_t)gr * EMBED + col] = f2bf((acc[ri][j][rg] + bb) * scale);
                }
            }
        }
    }
}

// ---------------- fused logits + softmax: one wave per feature ----------------
__global__ __launch_bounds__(256) void logits_sm_kernel(
    const short* __restrict__ q, const short* __restrict__ k,
    const int* __restrict__ rbev, const int* __restrict__ starts,
    const int* __restrict__ lengths, int ref_num,
    float* __restrict__ Wsm, short* __restrict__ Wg)
{
    __shared__ float Ll[4][HEADS][48];
    int f = blockIdx.x * 4 + (threadIdx.x >> 6);
    if (f >= KLEN) return;
    int w = threadIdx.x >> 6;
    int lane = threadIdx.x & 63;
    int h = lane >> 3, c = lane & 7;
    int st = starts[f], len = lengths[f];

    bf16x4 kv = *(const bf16x4*)(k + (size_t)f * EMBED + lane * 4);
    float k0 = bf2f(kv[0]), k1 = bf2f(kv[1]), k2 = bf2f(kv[2]), k3 = bf2f(kv[3]);

    // preload this segment's bev indices into lane registers
    int bvals = (lane < len) ? rbev[st + lane] : 0;

    int j = 0;
    for (; j + 1 < len; j += 2) {
        int b0 = __shfl(bvals, j);
        int b1 = __shfl(bvals, j + 1);
        bf16x4 q0 = *(const bf16x4*)(q + (size_t)b0 * EMBED + lane * 4);
        bf16x4 q1 = *(const bf16x4*)(q + (size_t)b1 * EMBED + lane * 4);
        float s0 = bf2f(q0[0]) * k0 + bf2f(q0[1]) * k1 + bf2f(q0[2]) * k2 + bf2f(q0[3]) * k3;
        float s1 = bf2f(q1[0]) * k0 + bf2f(q1[1]) * k1 + bf2f(q1[2]) * k2 + bf2f(q1[3]) * k3;
        s0 += __shfl_xor(s0, 1); s0 += __shfl_xor(s0, 2); s0 += __shfl_xor(s0, 4);
        s1 += __shfl_xor(s1, 1); s1 += __shfl_xor(s1, 2); s1 += __shfl_xor(s1, 4);
        if (c == 0) { Ll[w][h][j] = s0; Ll[w][h][j + 1] = s1; }
    }
    if (j < len) {
        int b0 = __shfl(bvals, j);
        bf16x4 q0 = *(const bf16x4*)(q + (size_t)b0 * EMBED + lane * 4);
        float s0 = bf2f(q0[0]) * k0 + bf2f(q0[1]) * k1 + bf2f(q0[2]) * k2 + bf2f(q0[3]) * k3;
        s0 += __shfl_xor(s0, 1); s0 += __shfl_xor(s0, 2); s0 += __shfl_xor(s0, 4);
        if (c == 0) Ll[w][h][j] = s0;
    }
    asm volatile("" ::: "memory"); // wave-lockstep LDS: block compiler reordering

    float m = -3.0e38f;
    for (int jj = c; jj < len; jj += 8) m = fmaxf(m, Ll[w][h][jj]);
    m = fmaxf(m, __shfl_xor(m, 1));
    m = fmaxf(m, __shfl_xor(m, 2));
    m = fmaxf(m, __shfl_xor(m, 4));
    float sum = 0.f;
    for (int jj = c; jj < len; jj += 8) {
        float e = __expf(Ll[w][h][jj] - m);
        Ll[w][h][jj] = e;
        sum += e;
    }
    sum += __shfl_xor(sum, 1);
    sum += __shfl_xor(sum, 2);
    sum += __shfl_xor(sum, 4);
    float inv = 1.f / sum;
    float* row = Wsm + ((size_t)f * HEADS + h) * ref_num;
    for (int jj = c; jj < ref_num; jj += 8) {
        float wv = (jj < len) ? Ll[w][h][jj] * inv : 0.f;
        row[jj] = wv;
        if (jj < len) Wg[((size_t)f * ref_num + jj) * 8 + h] = f2bf(wv);
    }
}

// ---------------- block-scan (1024 thr, 32 elems/thread, 2 barriers) ----------------
__global__ __launch_bounds__(1024) void scan_kernel(
    const int* __restrict__ count, int n,
    int* __restrict__ offs, int* __restrict__ cursor)
{
    __shared__ int wsum[16];
    const int t = threadIdx.x;
    const int lane = t & 63, wid = t >> 6;
    const int base = t * 32;
    int loc[32];
    int s = 0;
#pragma unroll
    for (int i = 0; i < 32; ++i) {
        int idx = base + i;
        int c = (idx < n) ? count[idx] : 0;
        loc[i] = s;
        s += c;
    }
    int incl = wave_incl_scan(s);
    if (lane == 63) wsum[wid] = incl;
    __syncthreads();
    if (wid == 0) {
        int v = (lane < 16) ? wsum[lane] : 0;
        int vi = wave_incl_scan(v);
        if (lane < 16) wsum[lane] = vi;
    }
    __syncthreads();
    int waveoff = (wid > 0) ? wsum[wid - 1] : 0;
    int excl = waveoff + incl - s;
#pragma unroll
    for (int i = 0; i < 32; ++i) {
        int idx = base + i;
        if (idx < n) { offs[idx] = excl + loc[i]; cursor[idx] = excl + loc[i]; }
    }
    if (t == 0) offs[n] = wsum[15];
}

// ---------------- permutation fill: pack (f,j) ----------------
__global__ __launch_bounds__(256) void perm_kernel(
    const int* __restrict__ rbev, const int* __restrict__ rfeat,
    const int* __restrict__ starts, int N,
    int* __restrict__ cursor, int* __restrict__ perm)
{
    int n = blockIdx.x * 256 + threadIdx.x;
    if (n < N) {
        int b = rbev[n];
        int f = rfeat[n];
        int j = n - starts[f];
        int pos = atomicAdd(&cursor[b], 1);
        perm[pos] = (f << 6) | j;
    }
}

// ---------------- gather + layernorm fused: one wave per output row ----------------
__global__ __launch_bounds__(256) void gather_ln_kernel(
    const short* __restrict__ vbf, const short* __restrict__ Wg,
    const int* __restrict__ perm, const int* __restrict__ offs, int ref_num,
    const float* __restrict__ g, const float* __restrict__ b,
    float* __restrict__ out)
{
    int row = blockIdx.x * 4 + (threadIdx.x >> 6);
    if (row >= TGT) return;
    int lane = threadIdx.x & 63;
    int h = lane >> 3;
    int beg = offs[row], end = offs[row + 1];
    float4 acc = make_float4(0.f, 0.f, 0.f, 0.f);
    for (int i = beg; i < end; ++i) {
        int pk = perm[i];
        int f = pk >> 6, j = pk & 63;
        float wp = bf2f(Wg[((size_t)f * ref_num + j) * 8 + h]);
        bf16x4 vv = *(const bf16x4*)(vbf + (size_t)f * EMBED + lane * 4);
        acc.x += wp * bf2f(vv[0]);
        acc.y += wp * bf2f(vv[1]);
        acc.z += wp * bf2f(vv[2]);
        acc.w += wp * bf2f(vv[3]);
    }
    float mu = wave_sum(acc.x + acc.y + acc.z + acc.w) * (1.f / EMBED);
    float dx = acc.x - mu, dy = acc.y - mu, dz = acc.z - mu, dw = acc.w - mu;
    float var = wave_sum(dx * dx + dy * dy + dz * dz + dw * dw) * (1.f / EMBED);
    float rs = rsqrtf(var + LN_EPS);
    float4 gg = *(const float4*)(g + lane * 4);
    float4 bb = *(const float4*)(b + lane * 4);
    float4 y;
    y.x = dx * rs * gg.x + bb.x;
    y.y = dy * rs * gg.y + bb.y;
    y.z = dz * rs * gg.z + bb.z;
    y.w = dw * rs * gg.w + bb.w;
    *(float4*)(out + (size_t)row * EMBED + lane * 4) = y;
}

extern "C" void kernel_launch(void* const* d_in, const int* in_sizes, int n_in,
                              void* d_out, int out_size, void* d_ws, size_t ws_size,
                              hipStream_t stream) {
    const float* query  = (const float*)d_in[0];
    const float* key_in = (const float*)d_in[1];
    const float* value  = (const float*)d_in[2];
    const int* rfeat    = (const int*)d_in[3];
    const int* rbev     = (const int*)d_in[4];
    const int* starts   = (const int*)d_in[5];
    const int* lengths  = (const int*)d_in[6];
    const float* wq1 = (const float*)d_in[7];
    const float* bq1 = (const float*)d_in[8];
    const float* wq2 = (const float*)d_in[9];
    const float* bq2 = (const float*)d_in[10];
    const float* wk1 = (const float*)d_in[11];
    const float* bk1 = (const float*)d_in[12];
    const float* wk2 = (const float*)d_in[13];
    const float* bk2 = (const float*)d_in[14];
    const float* ln_g = (const float*)d_in[15];
    const float* ln_b = (const float*)d_in[16];

    const int N = in_sizes[3];
    const int rn = (out_size - TGT * EMBED) / (KLEN * HEADS); // ref_num

    float* outp = (float*)d_out;
    float* Wsm  = outp + (size_t)TGT * EMBED;

    // workspace layout
    short* qbuf = (short*)d_ws;                          // TGT*256 bf16
    short* kbuf = qbuf + (size_t)TGT * EMBED;            // KLEN*256 bf16
    short* vbf  = kbuf + (size_t)KLEN * EMBED;           // KLEN*256 bf16
    int* count  = (int*)(vbf + (size_t)KLEN * EMBED);    // TGT
    int* offs   = count + TGT;                           // TGT+1
    int* cursor = offs + TGT + 1;                        // TGT
    int* perm   = cursor + TGT;                          // N
    short* Wt   = (short*)(perm + N);                    // 4*131072 bf16
    short* Wg   = Wt + 4 * 131072;                       // KLEN*rn*8 bf16

    const float scaling = 0.1767766952966369f; // 32^-0.5

    hipMemsetAsync(count, 0, TGT * sizeof(int), stream);

    int hist_blocks = (N + 255) / 256;
    prep_kernel<<<4160 + hist_blocks, 256, 0, stream>>>(
        value, vbf, wq1, wq2, wk1, wk2, Wt, rbev, N, count);

    const int nQblk = (TGT + 31) / 32;
    const int nKblk = KLEN / 32;
    mlp_mfma_kernel<<<nQblk + nKblk, 512, 0, stream>>>(
        query, key_in, nQblk, Wt, bq1, bq2, bk1, bk2, scaling, qbuf, kbuf);

    logits_sm_kernel<<<(KLEN + 3) / 4, 256, 0, stream>>>(qbuf, kbuf, rbev, starts, lengths, rn, Wsm, Wg);

    scan_kernel<<<1, 1024, 0, stream>>>(count, TGT, offs, cursor);
    perm_kernel<<<(N + 255) / 256, 256, 0, stream>>>(rbev, rfeat, starts, N, cursor, perm);
    gather_ln_kernel<<<(TGT + 3) / 4, 256, 0, stream>>>(vbf, Wg, perm, offs, rn, ln_g, ln_b, outp);
}

// Round 6
// 298.846 us; speedup vs baseline: 6.8698x; 1.0772x over previous
//
#include <hip/hip_runtime.h>
#include <math.h>

#define TGT 32400
#define KLEN 16896
#define EMBED 256
#define HID 512
#define HEADS 8
#define HDIM 32
#define LN_EPS 1e-5f

typedef __attribute__((ext_vector_type(8))) short bf16x8;
typedef __attribute__((ext_vector_type(4))) short bf16x4;
typedef __attribute__((ext_vector_type(4))) float f32x4;

__device__ inline short f2bf(float f) {
    union { float f; unsigned u; } v; v.f = f;
    unsigned r = v.u + 0x7FFF + ((v.u >> 16) & 1);
    return (short)(r >> 16);
}
__device__ inline float bf2f(short s) {
    union { unsigned u; float f; } v;
    v.u = ((unsigned)(unsigned short)s) << 16;
    return v.f;
}

// ---------------- wave helpers (wave64) ----------------
__device__ inline float wave_sum(float v) {
#pragma unroll
    for (int o = 32; o; o >>= 1) v += __shfl_xor(v, o);
    return v;
}
__device__ inline int wave_incl_scan(int v) {
    int lane = threadIdx.x & 63;
#pragma unroll
    for (int o = 1; o < 64; o <<= 1) {
        int x = __shfl_up(v, o);
        if (lane >= o) v += x;
    }
    return v;
}

// ---------------- prep: 4x weight transpose->bf16 (coalesced reads), value->bf16, histogram ----------------
__global__ __launch_bounds__(256) void prep_kernel(
    const float* __restrict__ value, short* __restrict__ vbf,
    const float* __restrict__ wq1, const float* __restrict__ wq2,
    const float* __restrict__ wk1, const float* __restrict__ wk2,
    short* __restrict__ Wt,
    const int* __restrict__ rbev, int N, int* __restrict__ count)
{
    int bid = blockIdx.x;
    if (bid < 2112) {
        int idx = bid * 256 + threadIdx.x;
        const float4* s4 = (const float4*)value + (size_t)idx * 2;
        float4 a = s4[0], b = s4[1];
        bf16x8 pk;
        pk[0] = f2bf(a.x); pk[1] = f2bf(a.y); pk[2] = f2bf(a.z); pk[3] = f2bf(a.w);
        pk[4] = f2bf(b.x); pk[5] = f2bf(b.y); pk[6] = f2bf(b.z); pk[7] = f2bf(b.w);
        *(bf16x8*)(vbf + (size_t)idx * 8) = pk;
    } else if (bid < 4160) {
        int i = (bid - 2112) * 256 + threadIdx.x;   // 0..524287
        int m = i >> 17;
        int r17 = i & 131071;
        int logC = (m & 1) ? 8 : 9;                 // C=512 for layer-1, 256 for layer-2
        int C = 1 << logC;
        int c = r17 & (C - 1);
        int r = r17 >> logC;
        int R = 131072 >> logC;
        const float* W = (m == 0) ? wq1 : (m == 1) ? wq2 : (m == 2) ? wk1 : wk2;
        // coalesced read W[r17]; scattered write absorbed by L2 (2 MB output)
        Wt[(size_t)m * 131072 + (size_t)c * R + r] = f2bf(W[r17]);
    } else {
        int n = (bid - 4160) * 256 + threadIdx.x;
        if (n < N) atomicAdd(&count[rbev[n]], 1);
    }
}

// ---------------- MFMA fused 2-layer MLP, 64 rows/block, 8 waves, LDS union ----------------
// Xs view: stride 264 shorts (rows 0..63) aliases the low half of lds.
// Hs view: stride 520 shorts (rows 0..63) uses the full 66.5 KB after phase 1.
#define XS_STRIDE 264
#define HS_STRIDE 520
__global__ __launch_bounds__(512, 2) void mlp_mfma_kernel(
    const float* __restrict__ Xq, const float* __restrict__ Xk, int nQblk,
    const short* __restrict__ Wt,  // [Wq1t, Wq2t, Wk1t, Wk2t] x 131072
    const float* __restrict__ bq1, const float* __restrict__ bq2,
    const float* __restrict__ bk1, const float* __restrict__ bk2,
    float scaleQ,
    short* __restrict__ Yq, short* __restrict__ Yk)
{
    __shared__ short lds[64 * HS_STRIDE];   // 66560 B

    const bool isQ = (int)blockIdx.x < nQblk;
    const int blk = isQ ? blockIdx.x : blockIdx.x - nQblk;
    const int M = isQ ? TGT : KLEN;
    const float* X = isQ ? Xq : Xk;
    const short* W1t = Wt + (isQ ? 0 : 2) * 131072;  // [512][256]
    const short* W2t = Wt + (isQ ? 1 : 3) * 131072;  // [256][512]
    const float* b1 = isQ ? bq1 : bk1;
    const float* b2 = isQ ? bq2 : bk2;
    const float scale = isQ ? scaleQ : 1.0f;
    short* Y = isQ ? Yq : Yk;

    const int t = threadIdx.x;
    const int wid = t >> 6;      // 0..7
    const int lane = t & 63;
    const int lrow = lane & 15;
    const int kch = lane >> 4;   // 0..3
    const int row0 = blk * 64;

    // ---- stage X tile: 64 rows x 256 cols, fp32 -> bf16 LDS (Xs view) ----
#pragma unroll
    for (int i = 0; i < 4; ++i) {
        int chunk = t + 512 * i;          // 2048 chunks of 8 elems
        int r = chunk >> 5;
        int cc = (chunk & 31) * 8;
        int gr = row0 + r; if (gr > M - 1) gr = M - 1;
        const float4* src = (const float4*)(X + (size_t)gr * EMBED + cc);
        float4 a = src[0], b = src[1];
        bf16x8 pk;
        pk[0] = f2bf(a.x); pk[1] = f2bf(a.y); pk[2] = f2bf(a.z); pk[3] = f2bf(a.w);
        pk[4] = f2bf(b.x); pk[5] = f2bf(b.y); pk[6] = f2bf(b.z); pk[7] = f2bf(b.w);
        *(bf16x8*)(&lds[r * XS_STRIDE + cc]) = pk;
    }
    __syncthreads();

    // ---- phase 1: H = relu(X@W1 + b1); wave owns hid cols [64*wid, +64) ----
    {
        f32x4 acc[4][4];   // [row-tile][j]
#pragma unroll
        for (int rt = 0; rt < 4; ++rt)
#pragma unroll
            for (int j = 0; j < 4; ++j) acc[rt][j] = (f32x4){0.f, 0.f, 0.f, 0.f};

        const int colBase = 64 * wid + lrow;
        bf16x8 wf[4], wn[4];
#pragma unroll
        for (int j = 0; j < 4; ++j)
            wf[j] = *(const bf16x8*)(W1t + (size_t)(colBase + 16 * j) * EMBED + 8 * kch);

#pragma unroll
        for (int ks = 0; ks < 8; ++ks) {
            int k0 = 32 * ks + 8 * kch;
            if (ks < 7) {
#pragma unroll
                for (int j = 0; j < 4; ++j)
                    wn[j] = *(const bf16x8*)(W1t + (size_t)(colBase + 16 * j) * EMBED + k0 + 32);
            }
            bf16x8 af[4];
#pragma unroll
            for (int rt = 0; rt < 4; ++rt)
                af[rt] = *(const bf16x8*)(&lds[(16 * rt + lrow) * XS_STRIDE + k0]);
#pragma unroll
            for (int j = 0; j < 4; ++j)
#pragma unroll
                for (int rt = 0; rt < 4; ++rt)
                    acc[rt][j] = __builtin_amdgcn_mfma_f32_16x16x32_bf16(af[rt], wf[j], acc[rt][j], 0, 0, 0);
#pragma unroll
            for (int j = 0; j < 4; ++j) wf[j] = wn[j];
        }

        __syncthreads();   // all waves done reading Xs; Hs aliases it

        // epilogue: bias + relu -> Hs (bf16)
#pragma unroll
        for (int j = 0; j < 4; ++j) {
            int col = 64 * wid + 16 * j + lrow;
            float bb = b1[col];
#pragma unroll
            for (int rt = 0; rt < 4; ++rt) {
#pragma unroll
                for (int rg = 0; rg < 4; ++rg) {
                    int r = 16 * rt + 4 * kch + rg;
                    lds[r * HS_STRIDE + col] = f2bf(fmaxf(acc[rt][j][rg] + bb, 0.f));
                }
            }
        }
    }
    __syncthreads();

    // ---- phase 2 (transposed): Y^T tile = W2^T @ H; wave owns Y cols [32*wid, +32) ----
    {
        f32x4 acc[2][4];   // [ct][row-tile]
#pragma unroll
        for (int ct = 0; ct < 2; ++ct)
#pragma unroll
            for (int rt = 0; rt < 4; ++rt) acc[ct][rt] = (f32x4){0.f, 0.f, 0.f, 0.f};

        const int colBase = 32 * wid + lrow;
        bf16x8 wf[2], wn[2];
#pragma unroll
        for (int ct = 0; ct < 2; ++ct)
            wf[ct] = *(const bf16x8*)(W2t + (size_t)(colBase + 16 * ct) * HID + 8 * kch);

#pragma unroll
        for (int ks = 0; ks < 16; ++ks) {
            int k0 = 32 * ks + 8 * kch;
            if (ks < 15) {
#pragma unroll
                for (int ct = 0; ct < 2; ++ct)
                    wn[ct] = *(const bf16x8*)(W2t + (size_t)(colBase + 16 * ct) * HID + k0 + 32);
            }
            bf16x8 hf[4];
#pragma unroll
            for (int rt = 0; rt < 4; ++rt)
                hf[rt] = *(const bf16x8*)(&lds[(16 * rt + lrow) * HS_STRIDE + k0]);
#pragma unroll
            for (int ct = 0; ct < 2; ++ct)
#pragma unroll
                for (int rt = 0; rt < 4; ++rt)
                    acc[ct][rt] = __builtin_amdgcn_mfma_f32_16x16x32_bf16(wf[ct], hf[rt], acc[ct][rt], 0, 0, 0);
#pragma unroll
            for (int ct = 0; ct < 2; ++ct) wf[ct] = wn[ct];
        }

        // epilogue: D[row=ycol][col=yrow]; lane's 4 rg = 4 consecutive Y cols -> 8B store
#pragma unroll
        for (int ct = 0; ct < 2; ++ct) {
            int yc0 = 32 * wid + 16 * ct + 4 * kch;
            float4 bb4 = *(const float4*)(b2 + yc0);
#pragma unroll
            for (int rt = 0; rt < 4; ++rt) {
                int gr = row0 + 16 * rt + lrow;
                if (gr < M) {
                    bf16x4 pk;
                    pk[0] = f2bf((acc[ct][rt][0] + bb4.x) * scale);
                    pk[1] = f2bf((acc[ct][rt][1] + bb4.y) * scale);
                    pk[2] = f2bf((acc[ct][rt][2] + bb4.z) * scale);
                    pk[3] = f2bf((acc[ct][rt][3] + bb4.w) * scale);
                    *(bf16x4*)(Y + (size_t)gr * EMBED + yc0) = pk;
                }
            }
        }
    }
}

// ---------------- fused logits + softmax: one wave per feature ----------------
__global__ __launch_bounds__(256) void logits_sm_kernel(
    const short* __restrict__ q, const short* __restrict__ k,
    const int* __restrict__ rbev, const int* __restrict__ starts,
    const int* __restrict__ lengths, int ref_num,
    float* __restrict__ Wsm, short* __restrict__ Wg)
{
    __shared__ float Ll[4][HEADS][48];
    int f = blockIdx.x * 4 + (threadIdx.x >> 6);
    if (f >= KLEN) return;
    int w = threadIdx.x >> 6;
    int lane = threadIdx.x & 63;
    int h = lane >> 3, c = lane & 7;
    int st = starts[f], len = lengths[f];

    bf16x4 kv = *(const bf16x4*)(k + (size_t)f * EMBED + lane * 4);
    float k0 = bf2f(kv[0]), k1 = bf2f(kv[1]), k2 = bf2f(kv[2]), k3 = bf2f(kv[3]);

    int bvals = (lane < len) ? rbev[st + lane] : 0;

    int j = 0;
    for (; j + 1 < len; j += 2) {
        int b0 = __shfl(bvals, j);
        int b1 = __shfl(bvals, j + 1);
        bf16x4 q0 = *(const bf16x4*)(q + (size_t)b0 * EMBED + lane * 4);
        bf16x4 q1 = *(const bf16x4*)(q + (size_t)b1 * EMBED + lane * 4);
        float s0 = bf2f(q0[0]) * k0 + bf2f(q0[1]) * k1 + bf2f(q0[2]) * k2 + bf2f(q0[3]) * k3;
        float s1 = bf2f(q1[0]) * k0 + bf2f(q1[1]) * k1 + bf2f(q1[2]) * k2 + bf2f(q1[3]) * k3;
        s0 += __shfl_xor(s0, 1); s0 += __shfl_xor(s0, 2); s0 += __shfl_xor(s0, 4);
        s1 += __shfl_xor(s1, 1); s1 += __shfl_xor(s1, 2); s1 += __shfl_xor(s1, 4);
        if (c == 0) { Ll[w][h][j] = s0; Ll[w][h][j + 1] = s1; }
    }
    if (j < len) {
        int b0 = __shfl(bvals, j);
        bf16x4 q0 = *(const bf16x4*)(q + (size_t)b0 * EMBED + lane * 4);
        float s0 = bf2f(q0[0]) * k0 + bf2f(q0[1]) * k1 + bf2f(q0[2]) * k2 + bf2f(q0[3]) * k3;
        s0 += __shfl_xor(s0, 1); s0 += __shfl_xor(s0, 2); s0 += __shfl_xor(s0, 4);
        if (c == 0) Ll[w][h][j] = s0;
    }
    asm volatile("" ::: "memory");

    float m = -3.0e38f;
    for (int jj = c; jj < len; jj += 8) m = fmaxf(m, Ll[w][h][jj]);
    m = fmaxf(m, __shfl_xor(m, 1));
    m = fmaxf(m, __shfl_xor(m, 2));
    m = fmaxf(m, __shfl_xor(m, 4));
    float sum = 0.f;
    for (int jj = c; jj < len; jj += 8) {
        float e = __expf(Ll[w][h][jj] - m);
        Ll[w][h][jj] = e;
        sum += e;
    }
    sum += __shfl_xor(sum, 1);
    sum += __shfl_xor(sum, 2);
    sum += __shfl_xor(sum, 4);
    float inv = 1.f / sum;
    float* row = Wsm + ((size_t)f * HEADS + h) * ref_num;
    for (int jj = c; jj < ref_num; jj += 8) {
        float wv = (jj < len) ? Ll[w][h][jj] * inv : 0.f;
        row[jj] = wv;
        if (jj < len) Wg[((size_t)f * ref_num + jj) * 8 + h] = f2bf(wv);
    }
}

// ---------------- block-scan (1024 thr, 32 elems/thread, 2 barriers) ----------------
__global__ __launch_bounds__(1024) void scan_kernel(
    const int* __restrict__ count, int n,
    int* __restrict__ offs, int* __restrict__ cursor)
{
    __shared__ int wsum[16];
    const int t = threadIdx.x;
    const int lane = t & 63, wid = t >> 6;
    const int base = t * 32;
    int loc[32];
    int s = 0;
#pragma unroll
    for (int i = 0; i < 32; ++i) {
        int idx = base + i;
        int c = (idx < n) ? count[idx] : 0;
        loc[i] = s;
        s += c;
    }
    int incl = wave_incl_scan(s);
    if (lane == 63) wsum[wid] = incl;
    __syncthreads();
    if (wid == 0) {
        int v = (lane < 16) ? wsum[lane] : 0;
        int vi = wave_incl_scan(v);
        if (lane < 16) wsum[lane] = vi;
    }
    __syncthreads();
    int waveoff = (wid > 0) ? wsum[wid - 1] : 0;
    int excl = waveoff + incl - s;
#pragma unroll
    for (int i = 0; i < 32; ++i) {
        int idx = base + i;
        if (idx < n) { offs[idx] = excl + loc[i]; cursor[idx] = excl + loc[i]; }
    }
    if (t == 0) offs[n] = wsum[15];
}

// ---------------- permutation fill: pack (f,j) ----------------
__global__ __launch_bounds__(256) void perm_kernel(
    const int* __restrict__ rbev, const int* __restrict__ rfeat,
    const int* __restrict__ starts, int N,
    int* __restrict__ cursor, int* __restrict__ perm)
{
    int n = blockIdx.x * 256 + threadIdx.x;
    if (n < N) {
        int b = rbev[n];
        int f = rfeat[n];
        int j = n - starts[f];
        int pos = atomicAdd(&cursor[b], 1);
        perm[pos] = (f << 6) | j;
    }
}

// ---------------- gather + layernorm fused: one wave per output row ----------------
__global__ __launch_bounds__(256) void gather_ln_kernel(
    const short* __restrict__ vbf, const short* __restrict__ Wg,
    const int* __restrict__ perm, const int* __restrict__ offs, int ref_num,
    const float* __restrict__ g, const float* __restrict__ b,
    float* __restrict__ out)
{
    int row = blockIdx.x * 4 + (threadIdx.x >> 6);
    if (row >= TGT) return;
    int lane = threadIdx.x & 63;
    int h = lane >> 3;
    int beg = offs[row], end = offs[row + 1];
    float4 acc = make_float4(0.f, 0.f, 0.f, 0.f);
    for (int i = beg; i < end; ++i) {
        int pk = perm[i];
        int f = pk >> 6, j = pk & 63;
        float wp = bf2f(Wg[((size_t)f * ref_num + j) * 8 + h]);
        bf16x4 vv = *(const bf16x4*)(vbf + (size_t)f * EMBED + lane * 4);
        acc.x += wp * bf2f(vv[0]);
        acc.y += wp * bf2f(vv[1]);
        acc.z += wp * bf2f(vv[2]);
        acc.w += wp * bf2f(vv[3]);
    }
    float mu = wave_sum(acc.x + acc.y + acc.z + acc.w) * (1.f / EMBED);
    float dx = acc.x - mu, dy = acc.y - mu, dz = acc.z - mu, dw = acc.w - mu;
    float var = wave_sum(dx * dx + dy * dy + dz * dz + dw * dw) * (1.f / EMBED);
    float rs = rsqrtf(var + LN_EPS);
    float4 gg = *(const float4*)(g + lane * 4);
    float4 bb = *(const float4*)(b + lane * 4);
    float4 y;
    y.x = dx * rs * gg.x + bb.x;
    y.y = dy * rs * gg.y + bb.y;
    y.z = dz * rs * gg.z + bb.z;
    y.w = dw * rs * gg.w + bb.w;
    *(float4*)(out + (size_t)row * EMBED + lane * 4) = y;
}

extern "C" void kernel_launch(void* const* d_in, const int* in_sizes, int n_in,
                              void* d_out, int out_size, void* d_ws, size_t ws_size,
                              hipStream_t stream) {
    const float* query  = (const float*)d_in[0];
    const float* key_in = (const float*)d_in[1];
    const float* value  = (const float*)d_in[2];
    const int* rfeat    = (const int*)d_in[3];
    const int* rbev     = (const int*)d_in[4];
    const int* starts   = (const int*)d_in[5];
    const int* lengths  = (const int*)d_in[6];
    const float* wq1 = (const float*)d_in[7];
    const float* bq1 = (const float*)d_in[8];
    const float* wq2 = (const float*)d_in[9];
    const float* bq2 = (const float*)d_in[10];
    const float* wk1 = (const float*)d_in[11];
    const float* bk1 = (const float*)d_in[12];
    const float* wk2 = (const float*)d_in[13];
    const float* bk2 = (const float*)d_in[14];
    const float* ln_g = (const float*)d_in[15];
    const float* ln_b = (const float*)d_in[16];

    const int N = in_sizes[3];
    const int rn = (out_size - TGT * EMBED) / (KLEN * HEADS); // ref_num

    float* outp = (float*)d_out;
    float* Wsm  = outp + (size_t)TGT * EMBED;

    // workspace layout
    short* qbuf = (short*)d_ws;                          // TGT*256 bf16
    short* kbuf = qbuf + (size_t)TGT * EMBED;            // KLEN*256 bf16
    short* vbf  = kbuf + (size_t)KLEN * EMBED;           // KLEN*256 bf16
    int* count  = (int*)(vbf + (size_t)KLEN * EMBED);    // TGT
    int* offs   = count + TGT;                           // TGT+1
    int* cursor = offs + TGT + 1;                        // TGT
    int* perm   = cursor + TGT;                          // N
    short* Wt   = (short*)(perm + N);                    // 4*131072 bf16
    short* Wg   = Wt + 4 * 131072;                       // KLEN*rn*8 bf16

    const float scaling = 0.1767766952966369f; // 32^-0.5

    hipMemsetAsync(count, 0, TGT * sizeof(int), stream);

    int hist_blocks = (N + 255) / 256;
    prep_kernel<<<4160 + hist_blocks, 256, 0, stream>>>(
        value, vbf, wq1, wq2, wk1, wk2, Wt, rbev, N, count);

    const int nQblk = (TGT + 63) / 64;
    const int nKblk = KLEN / 64;
    mlp_mfma_kernel<<<nQblk + nKblk, 512, 0, stream>>>(
        query, key_in, nQblk, Wt, bq1, bq2, bk1, bk2, scaling, qbuf, kbuf);

    logits_sm_kernel<<<(KLEN + 3) / 4, 256, 0, stream>>>(qbuf, kbuf, rbev, starts, lengths, rn, Wsm, Wg);

    scan_kernel<<<1, 1024, 0, stream>>>(count, TGT, offs, cursor);
    perm_kernel<<<(N + 255) / 256, 256, 0, stream>>>(rbev, rfeat, starts, N, cursor, perm);
    gather_ln_kernel<<<(TGT + 3) / 4, 256, 0, stream>>>(vbf, Wg, perm, offs, rn, ln_g, ln_b, outp);
}

// Round 7
// 297.765 us; speedup vs baseline: 6.8947x; 1.0036x over previous
//
#include <hip/hip_runtime.h>
#include <math.h>

#define TGT 32400
#define KLEN 16896
#define EMBED 256
#define HID 512
#define HEADS 8
#define HDIM 32
#define LN_EPS 1e-5f

typedef __attribute__((ext_vector_type(8))) short bf16x8;
typedef __attribute__((ext_vector_type(4))) short bf16x4;
typedef __attribute__((ext_vector_type(4))) float f32x4;

__device__ inline short f2bf(float f) {
    union { float f; unsigned u; } v; v.f = f;
    unsigned r = v.u + 0x7FFF + ((v.u >> 16) & 1);
    return (short)(r >> 16);
}
__device__ inline float bf2f(short s) {
    union { unsigned u; float f; } v;
    v.u = ((unsigned)(unsigned short)s) << 16;
    return v.f;
}

__device__ inline void gload_lds16(const short* g, short* l) {
    __builtin_amdgcn_global_load_lds(
        (const __attribute__((address_space(1))) void*)g,
        (__attribute__((address_space(3))) void*)l,
        16, 0, 0);
}

// ---------------- wave helpers (wave64) ----------------
__device__ inline float wave_sum(float v) {
#pragma unroll
    for (int o = 32; o; o >>= 1) v += __shfl_xor(v, o);
    return v;
}
__device__ inline int wave_incl_scan(int v) {
    int lane = threadIdx.x & 63;
#pragma unroll
    for (int o = 1; o < 64; o <<= 1) {
        int x = __shfl_up(v, o);
        if (lane >= o) v += x;
    }
    return v;
}

// ---------------- prep: fp32->bf16 (value, query, key), weight transpose, histogram ----------------
// block ranges: [0,2112) value | [2112,6162) query | [6162,8274) key | [8274,10322) wtrans | [10322,..) hist
__global__ __launch_bounds__(256) void prep_kernel(
    const float* __restrict__ value, short* __restrict__ vbf,
    const float* __restrict__ query, short* __restrict__ xqbf,
    const float* __restrict__ key_in, short* __restrict__ xkbf,
    const float* __restrict__ wq1, const float* __restrict__ wq2,
    const float* __restrict__ wk1, const float* __restrict__ wk2,
    short* __restrict__ Wt,
    const int* __restrict__ rbev, int N, int* __restrict__ count)
{
    int bid = blockIdx.x;
    if (bid < 8274) {
        const float* src; short* dst; int idx;
        if (bid < 2112)      { src = value;  dst = vbf;  idx = bid * 256 + threadIdx.x; }
        else if (bid < 6162) { src = query;  dst = xqbf; idx = (bid - 2112) * 256 + threadIdx.x; }
        else                 { src = key_in; dst = xkbf; idx = (bid - 6162) * 256 + threadIdx.x; }
        const float4* s4 = (const float4*)src + (size_t)idx * 2;
        float4 a = s4[0], b = s4[1];
        bf16x8 pk;
        pk[0] = f2bf(a.x); pk[1] = f2bf(a.y); pk[2] = f2bf(a.z); pk[3] = f2bf(a.w);
        pk[4] = f2bf(b.x); pk[5] = f2bf(b.y); pk[6] = f2bf(b.z); pk[7] = f2bf(b.w);
        *(bf16x8*)(dst + (size_t)idx * 8) = pk;
    } else if (bid < 10322) {
        int i = (bid - 8274) * 256 + threadIdx.x;   // 0..524287
        int m = i >> 17;
        int r17 = i & 131071;
        int logC = (m & 1) ? 8 : 9;                 // layer1: C=512, layer2: C=256
        int C = 1 << logC;
        int c = r17 & (C - 1);
        int r = r17 >> logC;
        int R = 131072 >> logC;
        const float* W = (m == 0) ? wq1 : (m == 1) ? wq2 : (m == 2) ? wk1 : wk2;
        Wt[(size_t)m * 131072 + (size_t)c * R + r] = f2bf(W[r17]);
    } else {
        int n = (bid - 10322) * 256 + threadIdx.x;
        if (n < N) atomicAdd(&count[rbev[n]], 1);
    }
}

// ---------------- MFMA MLP: persistent, double-buffered DMA staging ----------------
// 64-row tiles, 8 waves. sX[2]: 64x256 bf16 linear w/ 16B-chunk XOR swizzle (DMA dest).
// sH: 64x512 bf16 linear w/ same swizzle (VALU-written).
__global__ __launch_bounds__(512, 2) void mlp_mfma_kernel(
    const short* __restrict__ xqbf, const short* __restrict__ xkbf,
    int nQblk, int nTiles,
    const short* __restrict__ Wt,
    const float* __restrict__ bq1, const float* __restrict__ bq2,
    const float* __restrict__ bk1, const float* __restrict__ bk2,
    float scaleQ,
    short* __restrict__ Yq, short* __restrict__ Yk)
{
    __shared__ short sX[2][16384];   // 2 x 32 KiB
    __shared__ short sH[32768];      // 64 KiB

    const int t = threadIdx.x;
    const int wid = t >> 6;
    const int lane = t & 63;
    const int lrow = lane & 15;
    const int kch = lane >> 4;

    // DMA one 64x256 bf16 tile (32 KiB) into sX[sel]; linear dest, swizzled source.
    auto stage = [&](int tl, int sel) {
        const bool isQ = tl < nQblk;
        const int blk = isQ ? tl : tl - nQblk;
        const short* Xb = isQ ? xqbf : xkbf;
        const int M = isQ ? TGT : KLEN;
        const int row0 = blk * 64;
#pragma unroll
        for (int i = 0; i < 4; ++i) {
            int baseslot = i * 512 + wid * 64;      // wave-uniform
            int slot = baseslot + lane;
            int r = slot >> 5;                       // tile row
            int d = slot & 31;                       // 16B-chunk within row
            int cs = d ^ (r & 7);                    // swizzled source chunk
            int gr = row0 + r; if (gr > M - 1) gr = M - 1;
            gload_lds16(Xb + (size_t)gr * 256 + cs * 8, &sX[sel][baseslot * 8]);
        }
    };

    int tile = blockIdx.x;
    int sel = 0;
    if (tile < nTiles) stage(tile, 0);

    for (; tile < nTiles; tile += gridDim.x) {
        const bool isQ = tile < nQblk;
        const int blk = isQ ? tile : tile - nQblk;
        const int M = isQ ? TGT : KLEN;
        const short* W1t = Wt + (isQ ? 0 : 2) * 131072;  // [512][256]
        const short* W2t = Wt + (isQ ? 1 : 3) * 131072;  // [256][512]
        const float* b1 = isQ ? bq1 : bk1;
        const float* b2 = isQ ? bq2 : bk2;
        const float scale = isQ ? scaleQ : 1.0f;
        short* Y = isQ ? Yq : Yk;
        const int row0 = blk * 64;
        const short* xs = sX[sel];

        __syncthreads();   // drains vmcnt(0): sX[sel] DMA complete; prev-tile LDS reads done

        // ---- phase 1: H = relu(X@W1+b1); swapped operands; wave owns hid cols [64*wid,+64) ----
        {
            const int colBase = 64 * wid + lrow;
            f32x4 acc[4][4];
#pragma unroll
            for (int rt = 0; rt < 4; ++rt)
#pragma unroll
                for (int j = 0; j < 4; ++j) acc[rt][j] = (f32x4){0.f, 0.f, 0.f, 0.f};

            bf16x8 w1r[8][4];
#pragma unroll
            for (int ks = 0; ks < 4; ++ks)
#pragma unroll
                for (int j = 0; j < 4; ++j)
                    w1r[ks][j] = *(const bf16x8*)(W1t + (size_t)(colBase + 16 * j) * 256 + 32 * ks + 8 * kch);

#pragma unroll
            for (int ks = 0; ks < 8; ++ks) {
                if (ks < 4) {
#pragma unroll
                    for (int j = 0; j < 4; ++j)
                        w1r[ks + 4][j] = *(const bf16x8*)(W1t + (size_t)(colBase + 16 * j) * 256 + 32 * (ks + 4) + 8 * kch);
                }
                bf16x8 af[4];
#pragma unroll
                for (int rt = 0; rt < 4; ++rt) {
                    int row = 16 * rt + lrow;
                    af[rt] = *(const bf16x8*)&xs[row * 256 + (((4 * ks + kch) ^ (row & 7)) << 3)];
                }
#pragma unroll
                for (int j = 0; j < 4; ++j)
#pragma unroll
                    for (int rt = 0; rt < 4; ++rt)
                        acc[rt][j] = __builtin_amdgcn_mfma_f32_16x16x32_bf16(w1r[ks][j], af[rt], acc[rt][j], 0, 0, 0);
            }
            // epilogue: lane holds H[xrow=16rt+lrow][64wid+16j+4kch+rg] -> 8B swizzled writes
#pragma unroll
            for (int j = 0; j < 4; ++j) {
                int col0 = 64 * wid + 16 * j + 4 * kch;
                float4 bb = *(const float4*)(b1 + col0);
#pragma unroll
                for (int rt = 0; rt < 4; ++rt) {
                    int row = 16 * rt + lrow;
                    bf16x4 pk;
                    pk[0] = f2bf(fmaxf(acc[rt][j][0] + bb.x, 0.f));
                    pk[1] = f2bf(fmaxf(acc[rt][j][1] + bb.y, 0.f));
                    pk[2] = f2bf(fmaxf(acc[rt][j][2] + bb.z, 0.f));
                    pk[3] = f2bf(fmaxf(acc[rt][j][3] + bb.w, 0.f));
                    int chunk = (col0 >> 3) ^ (row & 7);
                    *(bf16x4*)&sH[row * 512 + (chunk << 3) + (col0 & 7)] = pk;
                }
            }
        }
        __syncthreads();   // sH complete

        // ---- phase 2: Y = (H@W2+b2)*scale; wave owns out cols [32*wid,+32) ----
        {
            const int colBase = 32 * wid + lrow;
            f32x4 acc[2][4];
#pragma unroll
            for (int ct = 0; ct < 2; ++ct)
#pragma unroll
                for (int rt = 0; rt < 4; ++rt) acc[ct][rt] = (f32x4){0.f, 0.f, 0.f, 0.f};

            bf16x8 w2r[16][2];
#pragma unroll
            for (int ks = 0; ks < 8; ++ks)
#pragma unroll
                for (int ct = 0; ct < 2; ++ct)
                    w2r[ks][ct] = *(const bf16x8*)(W2t + (size_t)(colBase + 16 * ct) * 512 + 32 * ks + 8 * kch);

            // overlap next tile's X DMA with phase-2 compute
            {
                int nxt = tile + gridDim.x;
                if (nxt < nTiles) stage(nxt, sel ^ 1);
            }

#pragma unroll
            for (int ks = 0; ks < 16; ++ks) {
                if (ks < 8) {
#pragma unroll
                    for (int ct = 0; ct < 2; ++ct)
                        w2r[ks + 8][ct] = *(const bf16x8*)(W2t + (size_t)(colBase + 16 * ct) * 512 + 32 * (ks + 8) + 8 * kch);
                }
                bf16x8 hf[4];
#pragma unroll
                for (int rt = 0; rt < 4; ++rt) {
                    int row = 16 * rt + lrow;
                    hf[rt] = *(const bf16x8*)&sH[row * 512 + (((4 * ks + kch) ^ (row & 7)) << 3)];
                }
#pragma unroll
                for (int ct = 0; ct < 2; ++ct)
#pragma unroll
                    for (int rt = 0; rt < 4; ++rt)
                        acc[ct][rt] = __builtin_amdgcn_mfma_f32_16x16x32_bf16(w2r[ks][ct], hf[rt], acc[ct][rt], 0, 0, 0);
            }
            // epilogue -> Y (8B stores)
#pragma unroll
            for (int ct = 0; ct < 2; ++ct) {
                int yc0 = 32 * wid + 16 * ct + 4 * kch;
                float4 bb4 = *(const float4*)(b2 + yc0);
#pragma unroll
                for (int rt = 0; rt < 4; ++rt) {
                    int gr = row0 + 16 * rt + lrow;
                    if (gr < M) {
                        bf16x4 pk;
                        pk[0] = f2bf((acc[ct][rt][0] + bb4.x) * scale);
                        pk[1] = f2bf((acc[ct][rt][1] + bb4.y) * scale);
                        pk[2] = f2bf((acc[ct][rt][2] + bb4.z) * scale);
                        pk[3] = f2bf((acc[ct][rt][3] + bb4.w) * scale);
                        *(bf16x4*)(Y + (size_t)gr * EMBED + yc0) = pk;
                    }
                }
            }
        }
        sel ^= 1;
    }
}

// ---------------- fused logits + softmax: one wave per feature ----------------
__global__ __launch_bounds__(256) void logits_sm_kernel(
    const short* __restrict__ q, const short* __restrict__ k,
    const int* __restrict__ rbev, const int* __restrict__ starts,
    const int* __restrict__ lengths, int ref_num,
    float* __restrict__ Wsm, short* __restrict__ Wg)
{
    __shared__ float Ll[4][HEADS][48];
    int f = blockIdx.x * 4 + (threadIdx.x >> 6);
    if (f >= KLEN) return;
    int w = threadIdx.x >> 6;
    int lane = threadIdx.x & 63;
    int h = lane >> 3, c = lane & 7;
    int st = starts[f], len = lengths[f];

    bf16x4 kv = *(const bf16x4*)(k + (size_t)f * EMBED + lane * 4);
    float k0 = bf2f(kv[0]), k1 = bf2f(kv[1]), k2 = bf2f(kv[2]), k3 = bf2f(kv[3]);

    int bvals = (lane < len) ? rbev[st + lane] : 0;

    int j = 0;
    for (; j + 1 < len; j += 2) {
        int b0 = __shfl(bvals, j);
        int b1 = __shfl(bvals, j + 1);
        bf16x4 q0 = *(const bf16x4*)(q + (size_t)b0 * EMBED + lane * 4);
        bf16x4 q1 = *(const bf16x4*)(q + (size_t)b1 * EMBED + lane * 4);
        float s0 = bf2f(q0[0]) * k0 + bf2f(q0[1]) * k1 + bf2f(q0[2]) * k2 + bf2f(q0[3]) * k3;
        float s1 = bf2f(q1[0]) * k0 + bf2f(q1[1]) * k1 + bf2f(q1[2]) * k2 + bf2f(q1[3]) * k3;
        s0 += __shfl_xor(s0, 1); s0 += __shfl_xor(s0, 2); s0 += __shfl_xor(s0, 4);
        s1 += __shfl_xor(s1, 1); s1 += __shfl_xor(s1, 2); s1 += __shfl_xor(s1, 4);
        if (c == 0) { Ll[w][h][j] = s0; Ll[w][h][j + 1] = s1; }
    }
    if (j < len) {
        int b0 = __shfl(bvals, j);
        bf16x4 q0 = *(const bf16x4*)(q + (size_t)b0 * EMBED + lane * 4);
        float s0 = bf2f(q0[0]) * k0 + bf2f(q0[1]) * k1 + bf2f(q0[2]) * k2 + bf2f(q0[3]) * k3;
        s0 += __shfl_xor(s0, 1); s0 += __shfl_xor(s0, 2); s0 += __shfl_xor(s0, 4);
        if (c == 0) Ll[w][h][j] = s0;
    }
    asm volatile("" ::: "memory");

    float m = -3.0e38f;
    for (int jj = c; jj < len; jj += 8) m = fmaxf(m, Ll[w][h][jj]);
    m = fmaxf(m, __shfl_xor(m, 1));
    m = fmaxf(m, __shfl_xor(m, 2));
    m = fmaxf(m, __shfl_xor(m, 4));
    float sum = 0.f;
    for (int jj = c; jj < len; jj += 8) {
        float e = __expf(Ll[w][h][jj] - m);
        Ll[w][h][jj] = e;
        sum += e;
    }
    sum += __shfl_xor(sum, 1);
    sum += __shfl_xor(sum, 2);
    sum += __shfl_xor(sum, 4);
    float inv = 1.f / sum;
    float* row = Wsm + ((size_t)f * HEADS + h) * ref_num;
    for (int jj = c; jj < ref_num; jj += 8) {
        float wv = (jj < len) ? Ll[w][h][jj] * inv : 0.f;
        row[jj] = wv;
        if (jj < len) Wg[((size_t)f * ref_num + jj) * 8 + h] = f2bf(wv);
    }
}

// ---------------- block-scan (1024 thr, 32 elems/thread, 2 barriers) ----------------
__global__ __launch_bounds__(1024) void scan_kernel(
    const int* __restrict__ count, int n,
    int* __restrict__ offs, int* __restrict__ cursor)
{
    __shared__ int wsum[16];
    const int t = threadIdx.x;
    const int lane = t & 63, wid = t >> 6;
    const int base = t * 32;
    int loc[32];
    int s = 0;
#pragma unroll
    for (int i = 0; i < 32; ++i) {
        int idx = base + i;
        int c = (idx < n) ? count[idx] : 0;
        loc[i] = s;
        s += c;
    }
    int incl = wave_incl_scan(s);
    if (lane == 63) wsum[wid] = incl;
    __syncthreads();
    if (wid == 0) {
        int v = (lane < 16) ? wsum[lane] : 0;
        int vi = wave_incl_scan(v);
        if (lane < 16) wsum[lane] = vi;
    }
    __syncthreads();
    int waveoff = (wid > 0) ? wsum[wid - 1] : 0;
    int excl = waveoff + incl - s;
#pragma unroll
    for (int i = 0; i < 32; ++i) {
        int idx = base + i;
        if (idx < n) { offs[idx] = excl + loc[i]; cursor[idx] = excl + loc[i]; }
    }
    if (t == 0) offs[n] = wsum[15];
}

// ---------------- permutation fill: pack (f,j) ----------------
__global__ __launch_bounds__(256) void perm_kernel(
    const int* __restrict__ rbev, const int* __restrict__ rfeat,
    const int* __restrict__ starts, int N,
    int* __restrict__ cursor, int* __restrict__ perm)
{
    int n = blockIdx.x * 256 + threadIdx.x;
    if (n < N) {
        int b = rbev[n];
        int f = rfeat[n];
        int j = n - starts[f];
        int pos = atomicAdd(&cursor[b], 1);
        perm[pos] = (f << 6) | j;
    }
}

// ---------------- gather + layernorm fused: one wave per output row ----------------
__global__ __launch_bounds__(256) void gather_ln_kernel(
    const short* __restrict__ vbf, const short* __restrict__ Wg,
    const int* __restrict__ perm, const int* __restrict__ offs, int ref_num,
    const float* __restrict__ g, const float* __restrict__ b,
    float* __restrict__ out)
{
    int row = blockIdx.x * 4 + (threadIdx.x >> 6);
    if (row >= TGT) return;
    int lane = threadIdx.x & 63;
    int h = lane >> 3;
    int beg = offs[row], end = offs[row + 1];
    float4 acc = make_float4(0.f, 0.f, 0.f, 0.f);
    for (int i = beg; i < end; ++i) {
        int pk = perm[i];
        int f = pk >> 6, j = pk & 63;
        float wp = bf2f(Wg[((size_t)f * ref_num + j) * 8 + h]);
        bf16x4 vv = *(const bf16x4*)(vbf + (size_t)f * EMBED + lane * 4);
        acc.x += wp * bf2f(vv[0]);
        acc.y += wp * bf2f(vv[1]);
        acc.z += wp * bf2f(vv[2]);
        acc.w += wp * bf2f(vv[3]);
    }
    float mu = wave_sum(acc.x + acc.y + acc.z + acc.w) * (1.f / EMBED);
    float dx = acc.x - mu, dy = acc.y - mu, dz = acc.z - mu, dw = acc.w - mu;
    float var = wave_sum(dx * dx + dy * dy + dz * dz + dw * dw) * (1.f / EMBED);
    float rs = rsqrtf(var + LN_EPS);
    float4 gg = *(const float4*)(g + lane * 4);
    float4 bb = *(const float4*)(b + lane * 4);
    float4 y;
    y.x = dx * rs * gg.x + bb.x;
    y.y = dy * rs * gg.y + bb.y;
    y.z = dz * rs * gg.z + bb.z;
    y.w = dw * rs * gg.w + bb.w;
    *(float4*)(out + (size_t)row * EMBED + lane * 4) = y;
}

extern "C" void kernel_launch(void* const* d_in, const int* in_sizes, int n_in,
                              void* d_out, int out_size, void* d_ws, size_t ws_size,
                              hipStream_t stream) {
    const float* query  = (const float*)d_in[0];
    const float* key_in = (const float*)d_in[1];
    const float* value  = (const float*)d_in[2];
    const int* rfeat    = (const int*)d_in[3];
    const int* rbev     = (const int*)d_in[4];
    const int* starts   = (const int*)d_in[5];
    const int* lengths  = (const int*)d_in[6];
    const float* wq1 = (const float*)d_in[7];
    const float* bq1 = (const float*)d_in[8];
    const float* wq2 = (const float*)d_in[9];
    const float* bq2 = (const float*)d_in[10];
    const float* wk1 = (const float*)d_in[11];
    const float* bk1 = (const float*)d_in[12];
    const float* wk2 = (const float*)d_in[13];
    const float* bk2 = (const float*)d_in[14];
    const float* ln_g = (const float*)d_in[15];
    const float* ln_b = (const float*)d_in[16];

    const int N = in_sizes[3];
    const int rn = (out_size - TGT * EMBED) / (KLEN * HEADS); // ref_num

    float* outp = (float*)d_out;
    float* Wsm  = outp + (size_t)TGT * EMBED;

    // workspace layout
    short* qbuf = (short*)d_ws;                          // TGT*256 bf16 (MLP out)
    short* kbuf = qbuf + (size_t)TGT * EMBED;            // KLEN*256 bf16
    short* vbf  = kbuf + (size_t)KLEN * EMBED;           // KLEN*256 bf16
    short* xqbf = vbf + (size_t)KLEN * EMBED;            // TGT*256 bf16 (query in)
    short* xkbf = xqbf + (size_t)TGT * EMBED;            // KLEN*256 bf16 (key in)
    int* count  = (int*)(xkbf + (size_t)KLEN * EMBED);   // TGT
    int* offs   = count + TGT;                           // TGT+1
    int* cursor = offs + TGT + 1;                        // TGT
    int* perm   = cursor + TGT;                          // N
    short* Wt   = (short*)(perm + N);                    // 4*131072 bf16
    short* Wg   = Wt + 4 * 131072;                       // KLEN*rn*8 bf16

    const float scaling = 0.1767766952966369f; // 32^-0.5

    hipMemsetAsync(count, 0, TGT * sizeof(int), stream);

    int hist_blocks = (N + 255) / 256;
    prep_kernel<<<10322 + hist_blocks, 256, 0, stream>>>(
        value, vbf, query, xqbf, key_in, xkbf,
        wq1, wq2, wk1, wk2, Wt, rbev, N, count);

    const int nQblk = (TGT + 63) / 64;   // 507
    const int nKblk = KLEN / 64;         // 264
    const int nTiles = nQblk + nKblk;    // 771
    mlp_mfma_kernel<<<256, 512, 0, stream>>>(
        xqbf, xkbf, nQblk, nTiles, Wt, bq1, bq2, bk1, bk2, scaling, qbuf, kbuf);

    logits_sm_kernel<<<(KLEN + 3) / 4, 256, 0, stream>>>(qbuf, kbuf, rbev, starts, lengths, rn, Wsm, Wg);

    scan_kernel<<<1, 1024, 0, stream>>>(count, TGT, offs, cursor);
    perm_kernel<<<(N + 255) / 256, 256, 0, stream>>>(rbev, rfeat, starts, N, cursor, perm);
    gather_ln_kernel<<<(TGT + 3) / 4, 256, 0, stream>>>(vbf, Wg, perm, offs, rn, ln_g, ln_b, outp);
}

// Round 8
// 267.238 us; speedup vs baseline: 7.6823x; 1.1142x over previous
//
#include <hip/hip_runtime.h>
#include <math.h>

#define TGT 32400
#define KLEN 16896
#define EMBED 256
#define HID 512
#define HEADS 8
#define LN_EPS 1e-5f

#define NQT 1013              // ceil(32400/32) layer tiles for Q
#define NKT 528               // 16896/32
#define HROWS ((NQT + NKT) * 32)   // 49312 rows in H buffer

typedef __attribute__((ext_vector_type(8))) short bf16x8;
typedef __attribute__((ext_vector_type(4))) short bf16x4;
typedef __attribute__((ext_vector_type(4))) float f32x4;

__device__ inline short f2bf(float f) {
    union { float f; unsigned u; } v; v.f = f;
    unsigned r = v.u + 0x7FFF + ((v.u >> 16) & 1);
    return (short)(r >> 16);
}
__device__ inline float bf2f(short s) {
    union { unsigned u; float f; } v;
    v.u = ((unsigned)(unsigned short)s) << 16;
    return v.f;
}
__device__ inline void gload_lds16(const short* g, short* l) {
    __builtin_amdgcn_global_load_lds(
        (const __attribute__((address_space(1))) void*)g,
        (__attribute__((address_space(3))) void*)l,
        16, 0, 0);
}

// ---------------- wave helpers (wave64) ----------------
__device__ inline float wave_sum(float v) {
#pragma unroll
    for (int o = 32; o; o >>= 1) v += __shfl_xor(v, o);
    return v;
}
__device__ inline int wave_incl_scan(int v) {
    int lane = threadIdx.x & 63;
#pragma unroll
    for (int o = 1; o < 64; o <<= 1) {
        int x = __shfl_up(v, o);
        if (lane >= o) v += x;
    }
    return v;
}

// ---------------- prep: value->bf16, weight transpose->bf16, histogram ----------------
__global__ __launch_bounds__(256) void prep_kernel(
    const float* __restrict__ value, short* __restrict__ vbf,
    const float* __restrict__ wq1, const float* __restrict__ wq2,
    const float* __restrict__ wk1, const float* __restrict__ wk2,
    short* __restrict__ Wt,
    const int* __restrict__ rbev, int N, int* __restrict__ count)
{
    int bid = blockIdx.x;
    if (bid < 2112) {
        int idx = bid * 256 + threadIdx.x;
        const float4* s4 = (const float4*)value + (size_t)idx * 2;
        float4 a = s4[0], b = s4[1];
        bf16x8 pk;
        pk[0] = f2bf(a.x); pk[1] = f2bf(a.y); pk[2] = f2bf(a.z); pk[3] = f2bf(a.w);
        pk[4] = f2bf(b.x); pk[5] = f2bf(b.y); pk[6] = f2bf(b.z); pk[7] = f2bf(b.w);
        *(bf16x8*)(vbf + (size_t)idx * 8) = pk;
    } else if (bid < 4160) {
        int i = (bid - 2112) * 256 + threadIdx.x;   // 0..524287
        int m = i >> 17;
        int r17 = i & 131071;
        int logC = (m & 1) ? 8 : 9;
        int C = 1 << logC;
        int c = r17 & (C - 1);
        int r = r17 >> logC;
        int R = 131072 >> logC;
        const float* W = (m == 0) ? wq1 : (m == 1) ? wq2 : (m == 2) ? wk1 : wk2;
        Wt[(size_t)m * 131072 + (size_t)c * R + r] = f2bf(W[r17]);
    } else {
        int n = (bid - 4160) * 256 + threadIdx.x;
        if (n < N) atomicAdd(&count[rbev[n]], 1);
    }
}

// ---------------- MLP layer 1: persistent, W1-in-registers ----------------
// H[row][hid] = relu(X@W1 + b1), 32-row tiles, X reg-staged fp32->bf16 into padded LDS.
#define XPAD 264
__global__ __launch_bounds__(512, 2) void mlpA_kernel(
    const float* __restrict__ Xq, const float* __restrict__ Xk,
    const short* __restrict__ Wt,
    const float* __restrict__ bq1, const float* __restrict__ bk1,
    short* __restrict__ Hg, int nQblocks)
{
    __shared__ short sX[2][32 * XPAD];   // 2 x 16.5 KiB

    const int t = threadIdx.x;
    const int wid = t >> 6, lane = t & 63;
    const int lrow = lane & 15, kch = lane >> 4;

    const bool isQ = (int)blockIdx.x < nQblocks;
    const int bid = isQ ? blockIdx.x : blockIdx.x - nQblocks;
    const int stride = isQ ? nQblocks : (gridDim.x - nQblocks);
    const int nT = isQ ? NQT : NKT;
    const int M = isQ ? TGT : KLEN;
    const float* X = isQ ? Xq : Xk;
    const short* W1t = Wt + (size_t)(isQ ? 0 : 2) * 131072;   // [512][256]
    const float* b1 = isQ ? bq1 : bk1;
    const int hbase = isQ ? 0 : NQT * 32;

    const int colBase = 64 * wid + lrow;

    // W1 fragments resident for kernel lifetime: 32 x bf16x8 = 128 VGPR
    bf16x8 w1r[8][4];
#pragma unroll
    for (int ks = 0; ks < 8; ++ks)
#pragma unroll
        for (int j = 0; j < 4; ++j)
            w1r[ks][j] = *(const bf16x8*)(W1t + (size_t)(colBase + 16 * j) * 256 + 32 * ks + 8 * kch);
    float4 bb[4];
#pragma unroll
    for (int j = 0; j < 4; ++j)
        bb[j] = *(const float4*)(b1 + 64 * wid + 16 * j + 4 * kch);

    const int srow = t >> 4, sp = t & 15;

    float4 r0[4], r1[4];
    int tile = bid;
    if (tile < nT) {
        int gr = tile * 32 + srow; if (gr > M - 1) gr = M - 1;
        const float* base = X + (size_t)gr * 256;
#pragma unroll
        for (int i = 0; i < 4; ++i) r0[i] = *(const float4*)(base + (sp + 16 * i) * 4);
    }
    int sel = 0;

    for (; tile < nT; tile += stride) {
        // write current tile's X (bf16) into sX[sel]
#pragma unroll
        for (int i = 0; i < 4; ++i) {
            int c = sp + 16 * i;
            bf16x4 pk;
            pk[0] = f2bf(r0[i].x); pk[1] = f2bf(r0[i].y);
            pk[2] = f2bf(r0[i].z); pk[3] = f2bf(r0[i].w);
            *(bf16x4*)&sX[sel][srow * XPAD + c * 4] = pk;
        }
        // issue next tile's global loads (latency hides under compute)
        int nx = tile + stride;
        if (nx < nT) {
            int gr = nx * 32 + srow; if (gr > M - 1) gr = M - 1;
            const float* base = X + (size_t)gr * 256;
#pragma unroll
            for (int i = 0; i < 4; ++i) r1[i] = *(const float4*)(base + (sp + 16 * i) * 4);
        }
        // drain only LDS writes (NOT the r1 global loads), then barrier
        asm volatile("s_waitcnt lgkmcnt(0)" ::: "memory");
        __builtin_amdgcn_sched_barrier(0);
        __builtin_amdgcn_s_barrier();
        asm volatile("" ::: "memory");

        // compute: H-tile = X-tile @ W1
        f32x4 acc[2][4];
#pragma unroll
        for (int rt = 0; rt < 2; ++rt)
#pragma unroll
            for (int j = 0; j < 4; ++j) acc[rt][j] = (f32x4){0.f, 0.f, 0.f, 0.f};

        const short* xs = sX[sel];
#pragma unroll
        for (int ks = 0; ks < 8; ++ks) {
            bf16x8 af[2];
#pragma unroll
            for (int rt = 0; rt < 2; ++rt)
                af[rt] = *(const bf16x8*)&xs[(16 * rt + lrow) * XPAD + 32 * ks + 8 * kch];
#pragma unroll
            for (int j = 0; j < 4; ++j)
#pragma unroll
                for (int rt = 0; rt < 2; ++rt)
                    acc[rt][j] = __builtin_amdgcn_mfma_f32_16x16x32_bf16(w1r[ks][j], af[rt], acc[rt][j], 0, 0, 0);
        }

        // epilogue: bias+relu -> H (8B stores, 32B-contiguous per row)
        int hr0 = hbase + tile * 32;
#pragma unroll
        for (int j = 0; j < 4; ++j) {
#pragma unroll
            for (int rt = 0; rt < 2; ++rt) {
                bf16x4 pk;
                pk[0] = f2bf(fmaxf(acc[rt][j][0] + bb[j].x, 0.f));
                pk[1] = f2bf(fmaxf(acc[rt][j][1] + bb[j].y, 0.f));
                pk[2] = f2bf(fmaxf(acc[rt][j][2] + bb[j].z, 0.f));
                pk[3] = f2bf(fmaxf(acc[rt][j][3] + bb[j].w, 0.f));
                *(bf16x4*)(Hg + (size_t)(hr0 + 16 * rt + lrow) * 512 + 64 * wid + 16 * j + 4 * kch) = pk;
            }
        }
#pragma unroll
        for (int i = 0; i < 4; ++i) r0[i] = r1[i];
        sel ^= 1;
    }
}

// ---------------- MLP layer 2: persistent, W2-in-registers, DMA-staged H ----------------
__global__ __launch_bounds__(512, 2) void mlpB_kernel(
    const short* __restrict__ Hg, const short* __restrict__ Wt,
    const float* __restrict__ bq2, const float* __restrict__ bk2,
    short* __restrict__ qbuf, short* __restrict__ kbuf,
    float scaleQ, int nQblocks)
{
    __shared__ short sX[2][32 * 512];   // 2 x 32 KiB

    const int t = threadIdx.x;
    const int wid = t >> 6, lane = t & 63;
    const int lrow = lane & 15, kch = lane >> 4;

    const bool isQ = (int)blockIdx.x < nQblocks;
    const int bid = isQ ? blockIdx.x : blockIdx.x - nQblocks;
    const int stride = isQ ? nQblocks : (gridDim.x - nQblocks);
    const int nT = isQ ? NQT : NKT;
    const int M = isQ ? TGT : KLEN;
    const short* W2t = Wt + (size_t)(isQ ? 1 : 3) * 131072;   // [256][512]
    const float* b2 = isQ ? bq2 : bk2;
    short* Y = isQ ? qbuf : kbuf;
    const int hbase = isQ ? 0 : NQT * 32;
    const float scale = isQ ? scaleQ : 1.0f;

    const int colBase = 32 * wid + lrow;

    // W2 fragments resident: 32 x bf16x8 = 128 VGPR
    bf16x8 w2r[16][2];
#pragma unroll
    for (int ks = 0; ks < 16; ++ks)
#pragma unroll
        for (int ct = 0; ct < 2; ++ct)
            w2r[ks][ct] = *(const bf16x8*)(W2t + (size_t)(colBase + 16 * ct) * 512 + 32 * ks + 8 * kch);
    float4 bb[2];
#pragma unroll
    for (int ct = 0; ct < 2; ++ct)
        bb[ct] = *(const float4*)(b2 + 32 * wid + 16 * ct + 4 * kch);

    // DMA one 32x512 bf16 tile (32 KiB); linear LDS dest, XOR-swizzled source
    auto stage = [&](int tt, int s) {
#pragma unroll
        for (int i = 0; i < 4; ++i) {
            int baseslot = i * 512 + wid * 64;   // wave-uniform
            int slot = baseslot + lane;
            int r = slot >> 6;                    // row 0..31
            int d = slot & 63;                    // 16B chunk in row
            int cs = d ^ (r & 7);
            gload_lds16(Hg + (size_t)(hbase + tt * 32 + r) * 512 + cs * 8,
                        &sX[s][baseslot * 8]);
        }
    };

    int tile = bid;
    int sel = 0;
    if (tile < nT) stage(tile, 0);

    for (; tile < nT; tile += stride) {
        // all VMEM (incl. this wave's sel-DMA) complete, then cross-wave barrier
        asm volatile("s_waitcnt vmcnt(0)" ::: "memory");
        __builtin_amdgcn_sched_barrier(0);
        __builtin_amdgcn_s_barrier();
        asm volatile("" ::: "memory");
        // issue next tile's DMA (safe: prior readers of sel^1 finished before barrier)
        int nx = tile + stride;
        if (nx < nT) stage(nx, sel ^ 1);
        __builtin_amdgcn_sched_barrier(0);

        f32x4 acc[2][2];
#pragma unroll
        for (int ct = 0; ct < 2; ++ct)
#pragma unroll
            for (int rt = 0; rt < 2; ++rt) acc[ct][rt] = (f32x4){0.f, 0.f, 0.f, 0.f};

        const short* xs = sX[sel];
#pragma unroll
        for (int ks = 0; ks < 16; ++ks) {
            bf16x8 hf[2];
#pragma unroll
            for (int rt = 0; rt < 2; ++rt) {
                int row = 16 * rt + lrow;
                hf[rt] = *(const bf16x8*)&xs[row * 512 + (((4 * ks + kch) ^ (row & 7)) << 3)];
            }
#pragma unroll
            for (int ct = 0; ct < 2; ++ct)
#pragma unroll
                for (int rt = 0; rt < 2; ++rt)
                    acc[ct][rt] = __builtin_amdgcn_mfma_f32_16x16x32_bf16(w2r[ks][ct], hf[rt], acc[ct][rt], 0, 0, 0);
        }

        int gr0 = tile * 32;
#pragma unroll
        for (int ct = 0; ct < 2; ++ct) {
#pragma unroll
            for (int rt = 0; rt < 2; ++rt) {
                int gr = gr0 + 16 * rt + lrow;
                if (gr < M) {
                    bf16x4 pk;
                    pk[0] = f2bf((acc[ct][rt][0] + bb[ct].x) * scale);
                    pk[1] = f2bf((acc[ct][rt][1] + bb[ct].y) * scale);
                    pk[2] = f2bf((acc[ct][rt][2] + bb[ct].z) * scale);
                    pk[3] = f2bf((acc[ct][rt][3] + bb[ct].w) * scale);
                    *(bf16x4*)(Y + (size_t)gr * EMBED + 32 * wid + 16 * ct + 4 * kch) = pk;
                }
            }
        }
        sel ^= 1;
    }
}

// ---------------- fused logits + softmax: one wave per feature ----------------
__global__ __launch_bounds__(256) void logits_sm_kernel(
    const short* __restrict__ q, const short* __restrict__ k,
    const int* __restrict__ rbev, const int* __restrict__ starts,
    const int* __restrict__ lengths, int ref_num,
    float* __restrict__ Wsm, short* __restrict__ Wg)
{
    __shared__ float Ll[4][HEADS][48];
    int f = blockIdx.x * 4 + (threadIdx.x >> 6);
    if (f >= KLEN) return;
    int w = threadIdx.x >> 6;
    int lane = threadIdx.x & 63;
    int h = lane >> 3, c = lane & 7;
    int st = starts[f], len = lengths[f];

    bf16x4 kv = *(const bf16x4*)(k + (size_t)f * EMBED + lane * 4);
    float k0 = bf2f(kv[0]), k1 = bf2f(kv[1]), k2 = bf2f(kv[2]), k3 = bf2f(kv[3]);

    int bvals = (lane < len) ? rbev[st + lane] : 0;

    int j = 0;
    for (; j + 1 < len; j += 2) {
        int b0 = __shfl(bvals, j);
        int b1 = __shfl(bvals, j + 1);
        bf16x4 q0 = *(const bf16x4*)(q + (size_t)b0 * EMBED + lane * 4);
        bf16x4 q1 = *(const bf16x4*)(q + (size_t)b1 * EMBED + lane * 4);
        float s0 = bf2f(q0[0]) * k0 + bf2f(q0[1]) * k1 + bf2f(q0[2]) * k2 + bf2f(q0[3]) * k3;
        float s1 = bf2f(q1[0]) * k0 + bf2f(q1[1]) * k1 + bf2f(q1[2]) * k2 + bf2f(q1[3]) * k3;
        s0 += __shfl_xor(s0, 1); s0 += __shfl_xor(s0, 2); s0 += __shfl_xor(s0, 4);
        s1 += __shfl_xor(s1, 1); s1 += __shfl_xor(s1, 2); s1 += __shfl_xor(s1, 4);
        if (c == 0) { Ll[w][h][j] = s0; Ll[w][h][j + 1] = s1; }
    }
    if (j < len) {
        int b0 = __shfl(bvals, j);
        bf16x4 q0 = *(const bf16x4*)(q + (size_t)b0 * EMBED + lane * 4);
        float s0 = bf2f(q0[0]) * k0 + bf2f(q0[1]) * k1 + bf2f(q0[2]) * k2 + bf2f(q0[3]) * k3;
        s0 += __shfl_xor(s0, 1); s0 += __shfl_xor(s0, 2); s0 += __shfl_xor(s0, 4);
        if (c == 0) Ll[w][h][j] = s0;
    }
    asm volatile("" ::: "memory");

    float m = -3.0e38f;
    for (int jj = c; jj < len; jj += 8) m = fmaxf(m, Ll[w][h][jj]);
    m = fmaxf(m, __shfl_xor(m, 1));
    m = fmaxf(m, __shfl_xor(m, 2));
    m = fmaxf(m, __shfl_xor(m, 4));
    float sum = 0.f;
    for (int jj = c; jj < len; jj += 8) {
        float e = __expf(Ll[w][h][jj] - m);
        Ll[w][h][jj] = e;
        sum += e;
    }
    sum += __shfl_xor(sum, 1);
    sum += __shfl_xor(sum, 2);
    sum += __shfl_xor(sum, 4);
    float inv = 1.f / sum;
    float* row = Wsm + ((size_t)f * HEADS + h) * ref_num;
    for (int jj = c; jj < ref_num; jj += 8) {
        float wv = (jj < len) ? Ll[w][h][jj] * inv : 0.f;
        row[jj] = wv;
        if (jj < len) Wg[((size_t)f * ref_num + jj) * 8 + h] = f2bf(wv);
    }
}

// ---------------- block-scan (1024 thr, 32 elems/thread, 2 barriers) ----------------
__global__ __launch_bounds__(1024) void scan_kernel(
    const int* __restrict__ count, int n,
    int* __restrict__ offs, int* __restrict__ cursor)
{
    __shared__ int wsum[16];
    const int t = threadIdx.x;
    const int lane = t & 63, wid = t >> 6;
    const int base = t * 32;
    int loc[32];
    int s = 0;
#pragma unroll
    for (int i = 0; i < 32; ++i) {
        int idx = base + i;
        int c = (idx < n) ? count[idx] : 0;
        loc[i] = s;
        s += c;
    }
    int incl = wave_incl_scan(s);
    if (lane == 63) wsum[wid] = incl;
    __syncthreads();
    if (wid == 0) {
        int v = (lane < 16) ? wsum[lane] : 0;
        int vi = wave_incl_scan(v);
        if (lane < 16) wsum[lane] = vi;
    }
    __syncthreads();
    int waveoff = (wid > 0) ? wsum[wid - 1] : 0;
    int excl = waveoff + incl - s;
#pragma unroll
    for (int i = 0; i < 32; ++i) {
        int idx = base + i;
        if (idx < n) { offs[idx] = excl + loc[i]; cursor[idx] = excl + loc[i]; }
    }
    if (t == 0) offs[n] = wsum[15];
}

// ---------------- permutation fill: pack (f,j) ----------------
__global__ __launch_bounds__(256) void perm_kernel(
    const int* __restrict__ rbev, const int* __restrict__ rfeat,
    const int* __restrict__ starts, int N,
    int* __restrict__ cursor, int* __restrict__ perm)
{
    int n = blockIdx.x * 256 + threadIdx.x;
    if (n < N) {
        int b = rbev[n];
        int f = rfeat[n];
        int j = n - starts[f];
        int pos = atomicAdd(&cursor[b], 1);
        perm[pos] = (f << 6) | j;
    }
}

// ---------------- gather + layernorm fused: one wave per output row ----------------
__global__ __launch_bounds__(256) void gather_ln_kernel(
    const short* __restrict__ vbf, const short* __restrict__ Wg,
    const int* __restrict__ perm, const int* __restrict__ offs, int ref_num,
    const float* __restrict__ g, const float* __restrict__ b,
    float* __restrict__ out)
{
    int row = blockIdx.x * 4 + (threadIdx.x >> 6);
    if (row >= TGT) return;
    int lane = threadIdx.x & 63;
    int h = lane >> 3;
    int beg = offs[row], end = offs[row + 1];
    float4 acc = make_float4(0.f, 0.f, 0.f, 0.f);
    for (int i = beg; i < end; ++i) {
        int pk = perm[i];
        int f = pk >> 6, j = pk & 63;
        float wp = bf2f(Wg[((size_t)f * ref_num + j) * 8 + h]);
        bf16x4 vv = *(const bf16x4*)(vbf + (size_t)f * EMBED + lane * 4);
        acc.x += wp * bf2f(vv[0]);
        acc.y += wp * bf2f(vv[1]);
        acc.z += wp * bf2f(vv[2]);
        acc.w += wp * bf2f(vv[3]);
    }
    float mu = wave_sum(acc.x + acc.y + acc.z + acc.w) * (1.f / EMBED);
    float dx = acc.x - mu, dy = acc.y - mu, dz = acc.z - mu, dw = acc.w - mu;
    float var = wave_sum(dx * dx + dy * dy + dz * dz + dw * dw) * (1.f / EMBED);
    float rs = rsqrtf(var + LN_EPS);
    float4 gg = *(const float4*)(g + lane * 4);
    float4 bb = *(const float4*)(b + lane * 4);
    float4 y;
    y.x = dx * rs * gg.x + bb.x;
    y.y = dy * rs * gg.y + bb.y;
    y.z = dz * rs * gg.z + bb.z;
    y.w = dw * rs * gg.w + bb.w;
    *(float4*)(out + (size_t)row * EMBED + lane * 4) = y;
}

extern "C" void kernel_launch(void* const* d_in, const int* in_sizes, int n_in,
                              void* d_out, int out_size, void* d_ws, size_t ws_size,
                              hipStream_t stream) {
    const float* query  = (const float*)d_in[0];
    const float* key_in = (const float*)d_in[1];
    const float* value  = (const float*)d_in[2];
    const int* rfeat    = (const int*)d_in[3];
    const int* rbev     = (const int*)d_in[4];
    const int* starts   = (const int*)d_in[5];
    const int* lengths  = (const int*)d_in[6];
    const float* wq1 = (const float*)d_in[7];
    const float* bq1 = (const float*)d_in[8];
    const float* wq2 = (const float*)d_in[9];
    const float* bq2 = (const float*)d_in[10];
    const float* wk1 = (const float*)d_in[11];
    const float* bk1 = (const float*)d_in[12];
    const float* wk2 = (const float*)d_in[13];
    const float* bk2 = (const float*)d_in[14];
    const float* ln_g = (const float*)d_in[15];
    const float* ln_b = (const float*)d_in[16];

    const int N = in_sizes[3];
    const int rn = (out_size - TGT * EMBED) / (KLEN * HEADS); // ref_num

    float* outp = (float*)d_out;
    float* Wsm  = outp + (size_t)TGT * EMBED;

    // workspace layout: H first (16B aligned at base)
    short* Hg   = (short*)d_ws;                          // HROWS*512 bf16 (50.5 MB)
    short* qbuf = Hg + (size_t)HROWS * 512;              // TGT*256 bf16
    short* kbuf = qbuf + (size_t)TGT * EMBED;            // KLEN*256 bf16
    short* vbf  = kbuf + (size_t)KLEN * EMBED;           // KLEN*256 bf16
    short* Wt   = vbf + (size_t)KLEN * EMBED;            // 4*131072 bf16
    short* Wg   = Wt + 4 * 131072;                       // KLEN*rn*8 bf16
    int* count  = (int*)(Wg + (size_t)KLEN * rn * 8);    // TGT
    int* offs   = count + TGT;                           // TGT+1
    int* cursor = offs + TGT + 1;                        // TGT
    int* perm   = cursor + TGT;                          // N

    const float scaling = 0.1767766952966369f; // 32^-0.5
    const int nQblocks = 168;                  // of 256: Q:K tile ratio 1013:528

    hipMemsetAsync(count, 0, TGT * sizeof(int), stream);

    int hist_blocks = (N + 255) / 256;
    prep_kernel<<<4160 + hist_blocks, 256, 0, stream>>>(
        value, vbf, wq1, wq2, wk1, wk2, Wt, rbev, N, count);

    mlpA_kernel<<<256, 512, 0, stream>>>(query, key_in, Wt, bq1, bk1, Hg, nQblocks);
    mlpB_kernel<<<256, 512, 0, stream>>>(Hg, Wt, bq2, bk2, qbuf, kbuf, scaling, nQblocks);

    logits_sm_kernel<<<(KLEN + 3) / 4, 256, 0, stream>>>(qbuf, kbuf, rbev, starts, lengths, rn, Wsm, Wg);

    scan_kernel<<<1, 1024, 0, stream>>>(count, TGT, offs, cursor);
    perm_kernel<<<(N + 255) / 256, 256, 0, stream>>>(rbev, rfeat, starts, N, cursor, perm);
    gather_ln_kernel<<<(TGT + 3) / 4, 256, 0, stream>>>(vbf, Wg, perm, offs, rn, ln_g, ln_b, outp);
}